// Round 7
// baseline (159.060 us; speedup 1.0000x reference)
//
#include <hip/hip_runtime.h>
#include <hip/hip_bf16.h>

// Single-head causal self-attention, B=4 T=4096 C=1024 H=128, f32 in/out.
// prep_w: W -> Wt bf16 [3][128][1024] n-major, via LDS transpose (coalesced)
// proj:   fused x@{Wk,Wq,Wv}, 512-thr blocks (8 waves x 48 cols), one x pass;
//         Q prescaled; V written transposed (Vt[b][h][t])
// attn:   flash causal, 512-thr blocks: QBLK=128 = 8 waves x 16 q-rows
//         sharing one K/V LDS staging (XOR-swizzled, pad-free -> 51200B LDS,
//         3 blocks/CU = 24 waves/CU cap). kv-split chunk=256, heavy-first,
//         XCD-pinned batch. Partials bf16.
// combine: merge <=16 kv-split partials per 128-row q-block.
//
// ws map (bytes):
//   Wt    [0,        786432)
//   Qb    [786432,   +4MB)
//   Kb    [+4MB)
//   Vt    [+4MB)                      -> 13369344
//   Opart [13369344, +1088*32KB)      -> 49020928   (bf16)
//   ml    [49020928, +1114112)        -> 50135040

typedef unsigned short u16;
typedef __attribute__((ext_vector_type(8))) __bf16 bf16x8;
typedef __attribute__((ext_vector_type(8))) u16 u16x8;
typedef __attribute__((ext_vector_type(4))) u16 u16x4;
typedef __attribute__((ext_vector_type(4))) float f32x4;

#define T_DIM 4096
#define C_DIM 1024
#define H_DIM 128
#define EPB 272  // entries per batch: sum_{qb<32} ceil((qb+1)/2), chunk=256
#define WS_SPLIT_NEED 50135040ull

static __device__ __forceinline__ f32x4 mfma16x16(u16x8 a, u16x8 b, f32x4 c) {
  return __builtin_amdgcn_mfma_f32_16x16x32_bf16(
      __builtin_bit_cast(bf16x8, a), __builtin_bit_cast(bf16x8, b), c, 0, 0, 0);
}

static __device__ __forceinline__ u16 f2bf(float f) {
  __hip_bfloat16 h = __float2bfloat16(f);
  return __builtin_bit_cast(u16, h);
}

static __device__ __forceinline__ float bf2f(u16 u) {
  unsigned x = (unsigned)u << 16;
  return __builtin_bit_cast(float, x);
}

// ---------------------------------------------------------------- prep_w ----
// grid (16, 3): transpose one 64k x 128n slab of W_w via LDS, coalesced both ways.
__global__ __launch_bounds__(256) void prep_w_kernel(
    const float* __restrict__ wk, const float* __restrict__ wq,
    const float* __restrict__ wv, u16* __restrict__ Wt) {
  __shared__ u16 L[64 * 136];
  const int w = blockIdx.y;
  const int k0 = blockIdx.x * 64;
  const float* W = (w == 0) ? wk : (w == 1) ? wq : wv;
  const int t = threadIdx.x;
#pragma unroll
  for (int p = 0; p < 8; ++p) {
    int idx = p * 256 + t;
    int k = idx >> 5, c4 = (idx & 31) * 4;
    float4 v = *(const float4*)&W[(size_t)(k0 + k) * H_DIM + c4];
    u16x4 bv;
    bv.x = f2bf(v.x); bv.y = f2bf(v.y); bv.z = f2bf(v.z); bv.w = f2bf(v.w);
    *(u16x4*)&L[k * 136 + c4] = bv;
  }
  __syncthreads();
#pragma unroll
  for (int p = 0; p < 4; ++p) {
    int cid = p * 256 + t;
    int n = cid >> 3, kc = (cid & 7) * 8;
    u16x8 o;
#pragma unroll
    for (int j = 0; j < 8; ++j) o[j] = L[(kc + j) * 136 + n];
    *(u16x8*)&Wt[(size_t)w * 131072 + (size_t)n * 1024 + k0 + kc] = o;
  }
}

// ------------------------------------------------------------------ proj ----
// 256 blocks x 64 rows, 512 threads (8 waves). One x-tile staging feeds all
// three Ws; wave owns cols384 = wave*48 + j*16 + lq, j=0..2
// ([0,128)=K, [128,256)=Q prescaled, [256,384)=V -> transposed via LDS).
__global__ __launch_bounds__(512, 4) void proj_kernel(
    const float* __restrict__ x, const u16* __restrict__ Wt,
    u16* __restrict__ Qb, u16* __restrict__ Kb, u16* __restrict__ Vt) {
  __shared__ __attribute__((aligned(16))) u16 smem[64 * 72 + 384 * 72];
  u16* Xl = smem;            // [64][64] pad 72
  u16* Wl = smem + 64 * 72;  // [384][64] pad 72
  const int m0 = blockIdx.x * 64;
  const int t = threadIdx.x;
  const int wave = t >> 6, lane = t & 63;
  const int g = lane >> 4, lq = lane & 15;

  f32x4 acc[4][3] = {};

  for (int k0 = 0; k0 < C_DIM; k0 += 64) {
    __syncthreads();
#pragma unroll
    for (int p = 0; p < 2; ++p) {  // stage x: 64x64 f32 -> bf16
      int idx = p * 512 + t;
      int row = idx >> 4, c4 = (idx & 15) * 4;
      float4 v = *(const float4*)&x[(size_t)(m0 + row) * C_DIM + k0 + c4];
      u16x4 bv;
      bv.x = f2bf(v.x); bv.y = f2bf(v.y); bv.z = f2bf(v.z); bv.w = f2bf(v.w);
      *(u16x4*)&Xl[row * 72 + c4] = bv;
    }
#pragma unroll
    for (int p = 0; p < 6; ++p) {  // stage Wt: 384 rows x 64 k
      int idx = p * 512 + t;
      int wrow = idx >> 3, col = (idx & 7) * 8;
      *(u16x8*)&Wl[wrow * 72 + col] =
          *(const u16x8*)&Wt[(size_t)(wrow >> 7) * 131072 +
                             (size_t)(wrow & 127) * 1024 + k0 + col];
    }
    __syncthreads();
#pragma unroll
    for (int kk = 0; kk < 2; ++kk) {
      u16x8 af[4], bfr[3];
#pragma unroll
      for (int i = 0; i < 4; ++i)
        af[i] = *(const u16x8*)&Xl[(i * 16 + lq) * 72 + kk * 32 + g * 8];
#pragma unroll
      for (int j = 0; j < 3; ++j)
        bfr[j] = *(const u16x8*)&Wl[(wave * 48 + j * 16 + lq) * 72 + kk * 32 +
                                    g * 8];
#pragma unroll
      for (int i = 0; i < 4; ++i)
#pragma unroll
        for (int j = 0; j < 3; ++j)
          acc[i][j] = mfma16x16(af[i], bfr[j], acc[i][j]);
    }
  }

  const float qscale = 0.08838834764831845f;  // 128^-0.5
#pragma unroll
  for (int j = 0; j < 3; ++j) {  // K and Q direct writes (wave-uniform branch)
    const int c384 = wave * 48 + j * 16;
    const int which = c384 >> 7;
    const int col = (c384 & 127) + lq;
    if (which == 0) {
#pragma unroll
      for (int i = 0; i < 4; ++i)
#pragma unroll
        for (int r = 0; r < 4; ++r)
          Kb[(size_t)(m0 + i * 16 + g * 4 + r) * H_DIM + col] =
              f2bf(acc[i][j][r]);
    } else if (which == 1) {
#pragma unroll
      for (int i = 0; i < 4; ++i)
#pragma unroll
        for (int r = 0; r < 4; ++r)
          Qb[(size_t)(m0 + i * 16 + g * 4 + r) * H_DIM + col] =
              f2bf(acc[i][j][r] * qscale);
    }
  }
  __syncthreads();
#pragma unroll
  for (int j = 0; j < 3; ++j) {  // V -> LDS transposed [128 h][64 m] pad 72
    const int c384 = wave * 48 + j * 16;
    if ((c384 >> 7) == 2) {
      const int v = (c384 & 127) + lq;
#pragma unroll
      for (int i = 0; i < 4; ++i)
#pragma unroll
        for (int r = 0; r < 4; ++r)
          smem[v * 72 + i * 16 + g * 4 + r] = f2bf(acc[i][j][r]);
    }
  }
  __syncthreads();
  {
    const int b = m0 >> 12;
    const int t0 = m0 & 4095;
#pragma unroll
    for (int p = 0; p < 2; ++p) {
      int h = p * 64 + (t >> 3), mc = (t & 7) * 8;
      *(u16x8*)&Vt[(size_t)b * (H_DIM * T_DIM) + (size_t)h * T_DIM + t0 + mc] =
          *(const u16x8*)&smem[h * 72 + mc];
    }
  }
}

// ------------------------------------------------------------------ attn ----
// 512 threads: 8 waves x 16 q-rows = QBLK 128 sharing one K/V staging.
// K/V LDS XOR-swizzled (chunk ^= row&7): conflict-free, pad-free.
// split: 1088 blocks, XCD-pinned batch, heavy entries first, chunk=256.
__global__ __launch_bounds__(512, 6) void attn_kernel(
    const u16* __restrict__ Qb, const u16* __restrict__ Kb,
    const u16* __restrict__ Vt, float* __restrict__ out,
    u16* __restrict__ Opart, float* __restrict__ ml, int split) {
  __shared__ __attribute__((aligned(16))) u16 Kl[64 * 128];  // swizzled
  __shared__ __attribute__((aligned(16))) u16 Vl[128 * 64];  // swizzled
  __shared__ __attribute__((aligned(16))) u16 Pl[8][16 * 72];
  const int t = threadIdx.x;
  const int wave = t >> 6, lane = t & 63;
  const int g = lane >> 4, lq = lane & 15;
  const int lsw = lane & 7;  // read-side swizzle key (= row&7 for row=16nf+lq)

  int b, qb, kvb, kve, pid;
  if (split) {
    int bid = (int)blockIdx.x;  // 1088 linear
    int xcd = bid & 7;
    b = xcd >> 1;  // batch pinned to an XCD pair -> K/V L2-local
    int e = (EPB - 1) - ((bid >> 3) * 2 + (bid & 1));  // heavy-first
    int a = 0;
#pragma unroll
    for (int c = 1; c <= 15; ++c)
      if (e >= c * (c + 1)) a = c;
    int off = e - a * (a + 1);
    int d = off / (a + 1);
    int ch = off - d * (a + 1);
    qb = 2 * a + d;
    kvb = ch * 256;
    pid = b * EPB + e;
    int kv_full = qb * 128 + 128;
    kve = (kvb + 256 < kv_full) ? kvb + 256 : kv_full;
  } else {
    b = (int)blockIdx.x & 3;
    qb = 31 - ((int)blockIdx.x >> 2);
    kvb = 0;
    kve = qb * 128 + 128;
    pid = 0;
  }
  const int rowq = qb * 128 + wave * 16;  // wave's first q-row

  u16x8 qf[4];  // 16 q-rows x 128, A-frag layout (prescaled)
  {
    const u16* Qp = Qb + (size_t)(b * T_DIM + rowq + lq) * H_DIM;
#pragma unroll
    for (int c = 0; c < 4; ++c) qf[c] = *(const u16x8*)&Qp[c * 32 + g * 8];
  }

  f32x4 ao[8] = {};
  float m_run[4], l_run[4];
#pragma unroll
  for (int r = 0; r < 4; ++r) { m_run[r] = -INFINITY; l_run[r] = 0.f; }

  const int krow = t >> 4, kcc = t & 15;  // K stage: 32 rows/pass, chunk id
  const int vrow = t >> 3, vcc = t & 7;   // V stage: 64 rows/pass, chunk id
  const u16* Kg0 = Kb + (size_t)b * T_DIM * H_DIM;
  const u16* Vg0 = Vt + (size_t)b * H_DIM * T_DIM;

  for (int kv0 = kvb; kv0 < kve; kv0 += 64) {
    __syncthreads();
#pragma unroll
    for (int p = 0; p < 2; ++p) {  // K tile [64][128], swizzled chunks
      int r = p * 32 + krow;
      *(u16x8*)&Kl[r * 128 + ((kcc ^ (r & 7)) * 8)] =
          *(const u16x8*)&Kg0[(size_t)(kv0 + r) * H_DIM + kcc * 8];
    }
#pragma unroll
    for (int p = 0; p < 2; ++p) {  // V tile [128 h][64 t], swizzled chunks
      int h = p * 64 + vrow;
      *(u16x8*)&Vl[h * 64 + ((vcc ^ (h & 7)) * 8)] =
          *(const u16x8*)&Vg0[(size_t)h * T_DIM + kv0 + vcc * 8];
    }
    __syncthreads();

    if (kv0 > rowq + 15) continue;  // fully masked for this wave (uniform)

    // S = Q K^T (Q prescaled): 4 col-frags x 4 k-chunks from swizzled LDS
    f32x4 s[4];
#pragma unroll
    for (int nf = 0; nf < 4; ++nf) s[nf] = f32x4{0.f, 0.f, 0.f, 0.f};
#pragma unroll
    for (int nf = 0; nf < 4; ++nf)
#pragma unroll
      for (int c = 0; c < 4; ++c) {
        u16x8 kf = *(const u16x8*)&Kl[(nf * 16 + lq) * 128 +
                                      (((c * 4 + g) ^ lsw) * 8)];
        s[nf] = mfma16x16(qf[c], kf, s[nf]);
      }

    if (kv0 + 63 > rowq) {  // diagonal overlap: elementwise causal mask
      int row = rowq + g * 4;
#pragma unroll
      for (int nf = 0; nf < 4; ++nf) {
        int col = kv0 + nf * 16 + lq;
#pragma unroll
        for (int r = 0; r < 4; ++r)
          if (col > row + r) s[nf][r] = -INFINITY;
      }
    }

    // online softmax; rows 4g..4g+3 live in 16-lane group g
    float mloc[4];
#pragma unroll
    for (int r = 0; r < 4; ++r)
      mloc[r] = fmaxf(fmaxf(s[0][r], s[1][r]), fmaxf(s[2][r], s[3][r]));
#pragma unroll
    for (int off = 1; off < 16; off <<= 1)
#pragma unroll
      for (int r = 0; r < 4; ++r)
        mloc[r] = fmaxf(mloc[r], __shfl_xor(mloc[r], off));

    float al[4], ps[4];
#pragma unroll
    for (int r = 0; r < 4; ++r) {
      float mn = fmaxf(m_run[r], mloc[r]);
      al[r] = __expf(m_run[r] - mn);
      m_run[r] = mn;
      ps[r] = 0.f;
    }
#pragma unroll
    for (int nf = 0; nf < 4; ++nf)
#pragma unroll
      for (int r = 0; r < 4; ++r) {
        float p = __expf(s[nf][r] - m_run[r]);
        s[nf][r] = p;
        ps[r] += p;
      }
#pragma unroll
    for (int off = 1; off < 16; off <<= 1)
#pragma unroll
      for (int r = 0; r < 4; ++r) ps[r] += __shfl_xor(ps[r], off);
#pragma unroll
    for (int r = 0; r < 4; ++r) l_run[r] = l_run[r] * al[r] + ps[r];

    // defer-rescale: skip O-wide pass when max unchanged (wave-uniform)
    bool nochg = (al[0] == 1.f) && (al[1] == 1.f) && (al[2] == 1.f) &&
                 (al[3] == 1.f);
    if (!__all(nochg)) {
#pragma unroll
      for (int h8 = 0; h8 < 8; ++h8)
#pragma unroll
        for (int r = 0; r < 4; ++r) ao[h8][r] *= al[r];
    }

    // P (D-layout) -> per-wave LDS -> A-layout frags
#pragma unroll
    for (int nf = 0; nf < 4; ++nf)
#pragma unroll
      for (int r = 0; r < 4; ++r)
        Pl[wave][(g * 4 + r) * 72 + nf * 16 + lq] = f2bf(s[nf][r]);

    u16x8 pf[2];
#pragma unroll
    for (int kk = 0; kk < 2; ++kk)
      pf[kk] = *(const u16x8*)&Pl[wave][lq * 72 + kk * 32 + g * 8];
#pragma unroll
    for (int h8 = 0; h8 < 8; ++h8)
#pragma unroll
      for (int kk = 0; kk < 2; ++kk) {
        u16x8 vf = *(const u16x8*)&Vl[(h8 * 16 + lq) * 64 +
                                      (((kk * 4 + g) ^ lsw) * 8)];
        ao[h8] = mfma16x16(pf[kk], vf, ao[h8]);
      }
  }

  if (!split) {
    float inv[4];
#pragma unroll
    for (int r = 0; r < 4; ++r) inv[r] = 1.f / l_run[r];
    float* Og = out + (size_t)(b * T_DIM + rowq) * H_DIM;
#pragma unroll
    for (int h8 = 0; h8 < 8; ++h8)
#pragma unroll
      for (int r = 0; r < 4; ++r)
        Og[(size_t)(g * 4 + r) * H_DIM + h8 * 16 + lq] = ao[h8][r] * inv[r];
  } else {
    u16* Op = Opart + (size_t)pid * 16384 + (size_t)(wave * 16) * H_DIM;
#pragma unroll
    for (int h8 = 0; h8 < 8; ++h8)
#pragma unroll
      for (int r = 0; r < 4; ++r)
        Op[(g * 4 + r) * H_DIM + h8 * 16 + lq] = f2bf(ao[h8][r]);
    if (lq == 0) {
      float* mlp = ml + (size_t)pid * 256;
#pragma unroll
      for (int r = 0; r < 4; ++r) {
        int row = wave * 16 + g * 4 + r;
        mlp[row] = m_run[r];
        mlp[128 + row] = l_run[r];
      }
    }
  }
}

// --------------------------------------------------------------- combine ----
// grid (32, 4): merge the <=16 kv-split bf16 partials of one 128-row q-block.
__global__ __launch_bounds__(256) void combine_kernel(
    const u16* __restrict__ Opart, const float* __restrict__ ml,
    float* __restrict__ out) {
  const int qb = blockIdx.x, b = blockIdx.y;
  const int t = threadIdx.x;
  const int row = t >> 1;
  const int colb = (t & 1) * 64;
  const int a = qb >> 1;
  const int n = a + 1;
  const int base = a * (a + 1) + (qb & 1) * (a + 1);
  const int pid0 = b * EPB + base;

  float M = -INFINITY;
  for (int i = 0; i < n; ++i)
    M = fmaxf(M, ml[(size_t)(pid0 + i) * 256 + row]);

  float L = 0.f;
  float o[64] = {};
  for (int i = 0; i < n; ++i) {
    const size_t mb = (size_t)(pid0 + i) * 256;
    float sc = __expf(ml[mb + row] - M);
    L += sc * ml[mb + 128 + row];
    const u16* Op = Opart + (size_t)(pid0 + i) * 16384 + row * H_DIM + colb;
#pragma unroll
    for (int p = 0; p < 8; ++p) {
      u16x8 v = *(const u16x8*)&Op[p * 8];
#pragma unroll
      for (int e = 0; e < 8; ++e) o[p * 8 + e] += sc * bf2f(v[e]);
    }
  }
  float inv = 1.f / L;
  float* Og = out + ((size_t)b * T_DIM + qb * 128 + row) * H_DIM + colb;
#pragma unroll
  for (int p = 0; p < 16; ++p) {
    f32x4 v = {o[p * 4] * inv, o[p * 4 + 1] * inv, o[p * 4 + 2] * inv,
               o[p * 4 + 3] * inv};
    *(f32x4*)&Og[p * 4] = v;
  }
}

// ---------------------------------------------------------------- launch ----
extern "C" void kernel_launch(void* const* d_in, const int* in_sizes, int n_in,
                              void* d_out, int out_size, void* d_ws,
                              size_t ws_size, hipStream_t stream) {
  const float* x = (const float*)d_in[0];
  const float* wk = (const float*)d_in[1];
  const float* wq = (const float*)d_in[2];
  const float* wv = (const float*)d_in[3];
  float* out = (float*)d_out;
  char* ws = (char*)d_ws;

  u16* Wt = (u16*)ws;
  u16* Qb = (u16*)(ws + 786432);
  u16* Kb = (u16*)(ws + 786432 + 4194304);
  u16* Vt = (u16*)(ws + 786432 + 8388608);
  u16* Opart = (u16*)(ws + 13369344);
  float* ml = (float*)(ws + 49020928);

  const int split = (ws_size >= WS_SPLIT_NEED) ? 1 : 0;

  prep_w_kernel<<<dim3(16, 3), 256, 0, stream>>>(wk, wq, wv, Wt);
  proj_kernel<<<256, 512, 0, stream>>>(x, Wt, Qb, Kb, Vt);
  if (split) {
    attn_kernel<<<4 * EPB, 512, 0, stream>>>(Qb, Kb, Vt, out, Opart, ml, 1);
    combine_kernel<<<dim3(32, 4), 256, 0, stream>>>(Opart, ml, out);
  } else {
    attn_kernel<<<128, 512, 0, stream>>>(Qb, Kb, Vt, out, Opart, ml, 0);
  }
}

// Round 8
// 116.692 us; speedup vs baseline: 1.3631x; 1.3631x over previous
//
#include <hip/hip_runtime.h>
#include <hip/hip_bf16.h>

// Single-head causal self-attention, B=4 T=4096 C=1024 H=128, f32 in/out.
// prep_w: W -> Wt bf16 [3][128][1024] n-major, via LDS transpose (coalesced)
// proj:   fused x@{Wk,Wq,Wv}, 256-thr blocks (R6 known-good), one x pass;
//         Q prescaled; V written transposed (Vt[b][h][t])
// attn:   flash causal, 512-thr blocks: QBLK=128 = 8 waves x 16 q-rows
//         sharing one K/V LDS staging (XOR-swizzled, pad-free, 51200B LDS).
//         launch_bounds(512,4): 128-VGPR budget -> NO SPILL (R7 lesson:
//         (512,6) forced 40 VGPR -> 150MB scratch traffic).
//         kv-split chunk=256, heavy-first, XCD-pinned batch. Partials bf16.
// combine: merge <=16 kv-split partials per 128-row q-block.
//
// ws map (bytes):
//   Wt    [0,        786432)
//   Qb    [786432,   +4MB)
//   Kb    [+4MB)
//   Vt    [+4MB)                      -> 13369344
//   Opart [13369344, +1088*32KB)      -> 49020928   (bf16)
//   ml    [49020928, +1114112)        -> 50135040

typedef unsigned short u16;
typedef __attribute__((ext_vector_type(8))) __bf16 bf16x8;
typedef __attribute__((ext_vector_type(8))) u16 u16x8;
typedef __attribute__((ext_vector_type(4))) u16 u16x4;
typedef __attribute__((ext_vector_type(4))) float f32x4;

#define T_DIM 4096
#define C_DIM 1024
#define H_DIM 128
#define EPB 272  // entries per batch: sum_{qb<32} ceil((qb+1)/2), chunk=256
#define WS_SPLIT_NEED 50135040ull

static __device__ __forceinline__ f32x4 mfma16x16(u16x8 a, u16x8 b, f32x4 c) {
  return __builtin_amdgcn_mfma_f32_16x16x32_bf16(
      __builtin_bit_cast(bf16x8, a), __builtin_bit_cast(bf16x8, b), c, 0, 0, 0);
}

static __device__ __forceinline__ u16 f2bf(float f) {
  __hip_bfloat16 h = __float2bfloat16(f);
  return __builtin_bit_cast(u16, h);
}

static __device__ __forceinline__ float bf2f(u16 u) {
  unsigned x = (unsigned)u << 16;
  return __builtin_bit_cast(float, x);
}

// ---------------------------------------------------------------- prep_w ----
// grid (16, 3): transpose one 64k x 128n slab of W_w via LDS, coalesced both ways.
__global__ __launch_bounds__(256) void prep_w_kernel(
    const float* __restrict__ wk, const float* __restrict__ wq,
    const float* __restrict__ wv, u16* __restrict__ Wt) {
  __shared__ u16 L[64 * 136];
  const int w = blockIdx.y;
  const int k0 = blockIdx.x * 64;
  const float* W = (w == 0) ? wk : (w == 1) ? wq : wv;
  const int t = threadIdx.x;
#pragma unroll
  for (int p = 0; p < 8; ++p) {
    int idx = p * 256 + t;
    int k = idx >> 5, c4 = (idx & 31) * 4;
    float4 v = *(const float4*)&W[(size_t)(k0 + k) * H_DIM + c4];
    u16x4 bv;
    bv.x = f2bf(v.x); bv.y = f2bf(v.y); bv.z = f2bf(v.z); bv.w = f2bf(v.w);
    *(u16x4*)&L[k * 136 + c4] = bv;
  }
  __syncthreads();
#pragma unroll
  for (int p = 0; p < 4; ++p) {
    int cid = p * 256 + t;
    int n = cid >> 3, kc = (cid & 7) * 8;
    u16x8 o;
#pragma unroll
    for (int j = 0; j < 8; ++j) o[j] = L[(kc + j) * 136 + n];
    *(u16x8*)&Wt[(size_t)w * 131072 + (size_t)n * 1024 + k0 + kc] = o;
  }
}

// ------------------------------------------------------------------ proj ----
// R6 known-good: 256 blocks x 64 rows, 4 waves; all 4 waves compute
// (wave owns cols384 wave*96 + j*16 + lq, j=0..5).
__global__ __launch_bounds__(256, 1) void proj_kernel(
    const float* __restrict__ x, const u16* __restrict__ Wt,
    u16* __restrict__ Qb, u16* __restrict__ Kb, u16* __restrict__ Vt) {
  __shared__ __attribute__((aligned(16))) u16 smem[64 * 72 + 384 * 72];
  u16* Xl = smem;            // [64][64] pad 72
  u16* Wl = smem + 64 * 72;  // [384][64] pad 72
  const int m0 = blockIdx.x * 64;
  const int t = threadIdx.x;
  const int wave = t >> 6, lane = t & 63;
  const int g = lane >> 4, lq = lane & 15;

  f32x4 acc[4][6] = {};

  for (int k0 = 0; k0 < C_DIM; k0 += 64) {
    __syncthreads();
#pragma unroll
    for (int p = 0; p < 4; ++p) {  // stage x: 64x64 f32 -> bf16
      int idx = p * 256 + t;
      int row = idx >> 4, c4 = (idx & 15) * 4;
      float4 v = *(const float4*)&x[(size_t)(m0 + row) * C_DIM + k0 + c4];
      u16x4 bv;
      bv.x = f2bf(v.x); bv.y = f2bf(v.y); bv.z = f2bf(v.z); bv.w = f2bf(v.w);
      *(u16x4*)&Xl[row * 72 + c4] = bv;
    }
#pragma unroll
    for (int p = 0; p < 12; ++p) {  // stage Wt: 384 rows x 64 k
      int idx = p * 256 + t;
      int wrow = idx >> 3, col = (idx & 7) * 8;
      *(u16x8*)&Wl[wrow * 72 + col] =
          *(const u16x8*)&Wt[(size_t)(wrow >> 7) * 131072 +
                             (size_t)(wrow & 127) * 1024 + k0 + col];
    }
    __syncthreads();
#pragma unroll
    for (int kk = 0; kk < 2; ++kk) {
      u16x8 af[4], bfr[6];
#pragma unroll
      for (int i = 0; i < 4; ++i)
        af[i] = *(const u16x8*)&Xl[(i * 16 + lq) * 72 + kk * 32 + g * 8];
#pragma unroll
      for (int j = 0; j < 6; ++j)
        bfr[j] = *(const u16x8*)&Wl[(wave * 96 + j * 16 + lq) * 72 + kk * 32 +
                                    g * 8];
#pragma unroll
      for (int i = 0; i < 4; ++i)
#pragma unroll
        for (int j = 0; j < 6; ++j)
          acc[i][j] = mfma16x16(af[i], bfr[j], acc[i][j]);
    }
  }

  const float qscale = 0.08838834764831845f;  // 128^-0.5
#pragma unroll
  for (int j = 0; j < 6; ++j) {  // K and Q direct writes (wave-uniform branch)
    const int c384 = wave * 96 + j * 16;
    const int which = c384 >> 7;
    const int col = (c384 & 127) + lq;
    if (which == 0) {
#pragma unroll
      for (int i = 0; i < 4; ++i)
#pragma unroll
        for (int r = 0; r < 4; ++r)
          Kb[(size_t)(m0 + i * 16 + g * 4 + r) * H_DIM + col] =
              f2bf(acc[i][j][r]);
    } else if (which == 1) {
#pragma unroll
      for (int i = 0; i < 4; ++i)
#pragma unroll
        for (int r = 0; r < 4; ++r)
          Qb[(size_t)(m0 + i * 16 + g * 4 + r) * H_DIM + col] =
              f2bf(acc[i][j][r] * qscale);
    }
  }
  __syncthreads();
#pragma unroll
  for (int j = 0; j < 6; ++j) {  // V -> LDS transposed [128 h][64 m] pad 72
    const int c384 = wave * 96 + j * 16;
    if ((c384 >> 7) == 2) {
      const int v = (c384 & 127) + lq;
#pragma unroll
      for (int i = 0; i < 4; ++i)
#pragma unroll
        for (int r = 0; r < 4; ++r)
          smem[v * 72 + i * 16 + g * 4 + r] = f2bf(acc[i][j][r]);
    }
  }
  __syncthreads();
  {
    const int b = m0 >> 12;
    const int t0 = m0 & 4095;
#pragma unroll
    for (int p = 0; p < 4; ++p) {
      int idx = p * 256 + t;
      int h = idx >> 3, mc = (idx & 7) * 8;
      *(u16x8*)&Vt[(size_t)b * (H_DIM * T_DIM) + (size_t)h * T_DIM + t0 + mc] =
          *(const u16x8*)&smem[h * 72 + mc];
    }
  }
}

// ------------------------------------------------------------------ attn ----
// 512 threads: 8 waves x 16 q-rows = QBLK 128 sharing one K/V staging.
// K/V LDS XOR-swizzled (chunk ^= row&7): conflict-free, pad-free.
// launch_bounds(512,4): VGPR budget 128 -> no scratch spill (R7 lesson).
// split: 1088 blocks, XCD-pinned batch, heavy entries first, chunk=256.
__global__ __launch_bounds__(512, 4) void attn_kernel(
    const u16* __restrict__ Qb, const u16* __restrict__ Kb,
    const u16* __restrict__ Vt, float* __restrict__ out,
    u16* __restrict__ Opart, float* __restrict__ ml, int split) {
  __shared__ __attribute__((aligned(16))) u16 Kl[64 * 128];  // swizzled
  __shared__ __attribute__((aligned(16))) u16 Vl[128 * 64];  // swizzled
  __shared__ __attribute__((aligned(16))) u16 Pl[8][16 * 72];
  const int t = threadIdx.x;
  const int wave = t >> 6, lane = t & 63;
  const int g = lane >> 4, lq = lane & 15;
  const int lsw = lane & 7;  // read-side swizzle key (= row&7 for row=16nf+lq)

  int b, qb, kvb, kve, pid;
  if (split) {
    int bid = (int)blockIdx.x;  // 1088 linear
    int xcd = bid & 7;
    b = xcd >> 1;  // batch pinned to an XCD pair -> K/V L2-local
    int e = (EPB - 1) - ((bid >> 3) * 2 + (bid & 1));  // heavy-first
    int a = 0;
#pragma unroll
    for (int c = 1; c <= 15; ++c)
      if (e >= c * (c + 1)) a = c;
    int off = e - a * (a + 1);
    int d = off / (a + 1);
    int ch = off - d * (a + 1);
    qb = 2 * a + d;
    kvb = ch * 256;
    pid = b * EPB + e;
    int kv_full = qb * 128 + 128;
    kve = (kvb + 256 < kv_full) ? kvb + 256 : kv_full;
  } else {
    b = (int)blockIdx.x & 3;
    qb = 31 - ((int)blockIdx.x >> 2);
    kvb = 0;
    kve = qb * 128 + 128;
    pid = 0;
  }
  const int rowq = qb * 128 + wave * 16;  // wave's first q-row

  u16x8 qf[4];  // 16 q-rows x 128, A-frag layout (prescaled)
  {
    const u16* Qp = Qb + (size_t)(b * T_DIM + rowq + lq) * H_DIM;
#pragma unroll
    for (int c = 0; c < 4; ++c) qf[c] = *(const u16x8*)&Qp[c * 32 + g * 8];
  }

  f32x4 ao[8] = {};
  float m_run[4], l_run[4];
#pragma unroll
  for (int r = 0; r < 4; ++r) { m_run[r] = -INFINITY; l_run[r] = 0.f; }

  const int krow = t >> 4, kcc = t & 15;  // K stage: 32 rows/pass, chunk id
  const int vrow = t >> 3, vcc = t & 7;   // V stage: 64 rows/pass, chunk id
  const u16* Kg0 = Kb + (size_t)b * T_DIM * H_DIM;
  const u16* Vg0 = Vt + (size_t)b * H_DIM * T_DIM;

  for (int kv0 = kvb; kv0 < kve; kv0 += 64) {
    __syncthreads();
#pragma unroll
    for (int p = 0; p < 2; ++p) {  // K tile [64][128], swizzled chunks
      int r = p * 32 + krow;
      *(u16x8*)&Kl[r * 128 + ((kcc ^ (r & 7)) * 8)] =
          *(const u16x8*)&Kg0[(size_t)(kv0 + r) * H_DIM + kcc * 8];
    }
#pragma unroll
    for (int p = 0; p < 2; ++p) {  // V tile [128 h][64 t], swizzled chunks
      int h = p * 64 + vrow;
      *(u16x8*)&Vl[h * 64 + ((vcc ^ (h & 7)) * 8)] =
          *(const u16x8*)&Vg0[(size_t)h * T_DIM + kv0 + vcc * 8];
    }
    __syncthreads();

    if (kv0 > rowq + 15) continue;  // fully masked for this wave (uniform)

    // S = Q K^T (Q prescaled): 4 col-frags x 4 k-chunks from swizzled LDS
    f32x4 s[4];
#pragma unroll
    for (int nf = 0; nf < 4; ++nf) s[nf] = f32x4{0.f, 0.f, 0.f, 0.f};
#pragma unroll
    for (int nf = 0; nf < 4; ++nf)
#pragma unroll
      for (int c = 0; c < 4; ++c) {
        u16x8 kf = *(const u16x8*)&Kl[(nf * 16 + lq) * 128 +
                                      (((c * 4 + g) ^ lsw) * 8)];
        s[nf] = mfma16x16(qf[c], kf, s[nf]);
      }

    if (kv0 + 63 > rowq) {  // diagonal overlap: elementwise causal mask
      int row = rowq + g * 4;
#pragma unroll
      for (int nf = 0; nf < 4; ++nf) {
        int col = kv0 + nf * 16 + lq;
#pragma unroll
        for (int r = 0; r < 4; ++r)
          if (col > row + r) s[nf][r] = -INFINITY;
      }
    }

    // online softmax; rows 4g..4g+3 live in 16-lane group g
    float mloc[4];
#pragma unroll
    for (int r = 0; r < 4; ++r)
      mloc[r] = fmaxf(fmaxf(s[0][r], s[1][r]), fmaxf(s[2][r], s[3][r]));
#pragma unroll
    for (int off = 1; off < 16; off <<= 1)
#pragma unroll
      for (int r = 0; r < 4; ++r)
        mloc[r] = fmaxf(mloc[r], __shfl_xor(mloc[r], off));

    float al[4], ps[4];
#pragma unroll
    for (int r = 0; r < 4; ++r) {
      float mn = fmaxf(m_run[r], mloc[r]);
      al[r] = __expf(m_run[r] - mn);
      m_run[r] = mn;
      ps[r] = 0.f;
    }
#pragma unroll
    for (int nf = 0; nf < 4; ++nf)
#pragma unroll
      for (int r = 0; r < 4; ++r) {
        float p = __expf(s[nf][r] - m_run[r]);
        s[nf][r] = p;
        ps[r] += p;
      }
#pragma unroll
    for (int off = 1; off < 16; off <<= 1)
#pragma unroll
      for (int r = 0; r < 4; ++r) ps[r] += __shfl_xor(ps[r], off);
#pragma unroll
    for (int r = 0; r < 4; ++r) l_run[r] = l_run[r] * al[r] + ps[r];

    // defer-rescale: skip O-wide pass when max unchanged (wave-uniform)
    bool nochg = (al[0] == 1.f) && (al[1] == 1.f) && (al[2] == 1.f) &&
                 (al[3] == 1.f);
    if (!__all(nochg)) {
#pragma unroll
      for (int h8 = 0; h8 < 8; ++h8)
#pragma unroll
        for (int r = 0; r < 4; ++r) ao[h8][r] *= al[r];
    }

    // P (D-layout) -> per-wave LDS -> A-layout frags
#pragma unroll
    for (int nf = 0; nf < 4; ++nf)
#pragma unroll
      for (int r = 0; r < 4; ++r)
        Pl[wave][(g * 4 + r) * 72 + nf * 16 + lq] = f2bf(s[nf][r]);

    u16x8 pf[2];
#pragma unroll
    for (int kk = 0; kk < 2; ++kk)
      pf[kk] = *(const u16x8*)&Pl[wave][lq * 72 + kk * 32 + g * 8];
#pragma unroll
    for (int h8 = 0; h8 < 8; ++h8)
#pragma unroll
      for (int kk = 0; kk < 2; ++kk) {
        u16x8 vf = *(const u16x8*)&Vl[(h8 * 16 + lq) * 64 +
                                      (((kk * 4 + g) ^ lsw) * 8)];
        ao[h8] = mfma16x16(pf[kk], vf, ao[h8]);
      }
  }

  if (!split) {
    float inv[4];
#pragma unroll
    for (int r = 0; r < 4; ++r) inv[r] = 1.f / l_run[r];
    float* Og = out + (size_t)(b * T_DIM + rowq) * H_DIM;
#pragma unroll
    for (int h8 = 0; h8 < 8; ++h8)
#pragma unroll
      for (int r = 0; r < 4; ++r)
        Og[(size_t)(g * 4 + r) * H_DIM + h8 * 16 + lq] = ao[h8][r] * inv[r];
  } else {
    u16* Op = Opart + (size_t)pid * 16384 + (size_t)(wave * 16) * H_DIM;
#pragma unroll
    for (int h8 = 0; h8 < 8; ++h8)
#pragma unroll
      for (int r = 0; r < 4; ++r)
        Op[(g * 4 + r) * H_DIM + h8 * 16 + lq] = f2bf(ao[h8][r]);
    if (lq == 0) {
      float* mlp = ml + (size_t)pid * 256;
#pragma unroll
      for (int r = 0; r < 4; ++r) {
        int row = wave * 16 + g * 4 + r;
        mlp[row] = m_run[r];
        mlp[128 + row] = l_run[r];
      }
    }
  }
}

// --------------------------------------------------------------- combine ----
// grid (32, 4): merge the <=16 kv-split bf16 partials of one 128-row q-block.
__global__ __launch_bounds__(256) void combine_kernel(
    const u16* __restrict__ Opart, const float* __restrict__ ml,
    float* __restrict__ out) {
  const int qb = blockIdx.x, b = blockIdx.y;
  const int t = threadIdx.x;
  const int row = t >> 1;
  const int colb = (t & 1) * 64;
  const int a = qb >> 1;
  const int n = a + 1;
  const int base = a * (a + 1) + (qb & 1) * (a + 1);
  const int pid0 = b * EPB + base;

  float M = -INFINITY;
  for (int i = 0; i < n; ++i)
    M = fmaxf(M, ml[(size_t)(pid0 + i) * 256 + row]);

  float L = 0.f;
  float o[64] = {};
  for (int i = 0; i < n; ++i) {
    const size_t mb = (size_t)(pid0 + i) * 256;
    float sc = __expf(ml[mb + row] - M);
    L += sc * ml[mb + 128 + row];
    const u16* Op = Opart + (size_t)(pid0 + i) * 16384 + row * H_DIM + colb;
#pragma unroll
    for (int p = 0; p < 8; ++p) {
      u16x8 v = *(const u16x8*)&Op[p * 8];
#pragma unroll
      for (int e = 0; e < 8; ++e) o[p * 8 + e] += sc * bf2f(v[e]);
    }
  }
  float inv = 1.f / L;
  float* Og = out + ((size_t)b * T_DIM + qb * 128 + row) * H_DIM + colb;
#pragma unroll
  for (int p = 0; p < 16; ++p) {
    f32x4 v = {o[p * 4] * inv, o[p * 4 + 1] * inv, o[p * 4 + 2] * inv,
               o[p * 4 + 3] * inv};
    *(f32x4*)&Og[p * 4] = v;
  }
}

// ---------------------------------------------------------------- launch ----
extern "C" void kernel_launch(void* const* d_in, const int* in_sizes, int n_in,
                              void* d_out, int out_size, void* d_ws,
                              size_t ws_size, hipStream_t stream) {
  const float* x = (const float*)d_in[0];
  const float* wk = (const float*)d_in[1];
  const float* wq = (const float*)d_in[2];
  const float* wv = (const float*)d_in[3];
  float* out = (float*)d_out;
  char* ws = (char*)d_ws;

  u16* Wt = (u16*)ws;
  u16* Qb = (u16*)(ws + 786432);
  u16* Kb = (u16*)(ws + 786432 + 4194304);
  u16* Vt = (u16*)(ws + 786432 + 8388608);
  u16* Opart = (u16*)(ws + 13369344);
  float* ml = (float*)(ws + 49020928);

  const int split = (ws_size >= WS_SPLIT_NEED) ? 1 : 0;

  prep_w_kernel<<<dim3(16, 3), 256, 0, stream>>>(wk, wq, wv, Wt);
  proj_kernel<<<256, 256, 0, stream>>>(x, Wt, Qb, Kb, Vt);
  if (split) {
    attn_kernel<<<4 * EPB, 512, 0, stream>>>(Qb, Kb, Vt, out, Opart, ml, 1);
    combine_kernel<<<dim3(32, 4), 256, 0, stream>>>(Opart, ml, out);
  } else {
    attn_kernel<<<128, 512, 0, stream>>>(Qb, Kb, Vt, out, Opart, ml, 0);
  }
}

// Round 9
// 101.704 us; speedup vs baseline: 1.5639x; 1.1474x over previous
//
#include <hip/hip_runtime.h>
#include <hip/hip_bf16.h>

// Single-head causal self-attention, B=4 T=4096 C=1024 H=128, f32 in/out.
// prep_w: W -> Wt bf16 [3][128][1024] n-major, via LDS transpose (coalesced)
// proj:   fused x@{Wk,Wq,Wv}, 256-thr blocks; W staged via global_load_lds
//         (async, pre-swizzled source, linear LDS); Q prescaled; V transposed.
// attn:   flash causal, 512-thr: QBLK=128 = 8 waves x 16 q-rows, K/V staged
//         via global_load_lds into XOR-swizzled LDS (pre-swizzled source),
//         launch_bounds(512,4) -> no spill. kv-split chunk=256, heavy-first,
//         XCD-pinned batch. Partials bf16.
// combine: grid (128,4): 32 rows/block, <=16 partials, 16 acc/thread.
//
// ws map (bytes):
//   Wt    [0,        786432)
//   Qb    [786432,   +4MB)
//   Kb    [+4MB)
//   Vt    [+4MB)                      -> 13369344
//   Opart [13369344, +1088*32KB)      -> 49020928   (bf16)
//   ml    [49020928, +1114112)        -> 50135040

typedef unsigned short u16;
typedef __attribute__((ext_vector_type(8))) __bf16 bf16x8;
typedef __attribute__((ext_vector_type(8))) u16 u16x8;
typedef __attribute__((ext_vector_type(4))) u16 u16x4;
typedef __attribute__((ext_vector_type(4))) float f32x4;

#define T_DIM 4096
#define C_DIM 1024
#define H_DIM 128
#define EPB 272  // entries per batch: sum_{qb<32} ceil((qb+1)/2), chunk=256
#define WS_SPLIT_NEED 50135040ull

static __device__ __forceinline__ f32x4 mfma16x16(u16x8 a, u16x8 b, f32x4 c) {
  return __builtin_amdgcn_mfma_f32_16x16x32_bf16(
      __builtin_bit_cast(bf16x8, a), __builtin_bit_cast(bf16x8, b), c, 0, 0, 0);
}

static __device__ __forceinline__ u16 f2bf(float f) {
  __hip_bfloat16 h = __float2bfloat16(f);
  return __builtin_bit_cast(u16, h);
}

static __device__ __forceinline__ float bf2f(u16 u) {
  unsigned x = (unsigned)u << 16;
  return __builtin_bit_cast(float, x);
}

// async global->LDS, 16B per lane; lptr must be wave-uniform base.
static __device__ __forceinline__ void gll16(const u16* g, u16* l) {
  __builtin_amdgcn_global_load_lds(
      (const __attribute__((address_space(1))) void*)(void*)g,
      (__attribute__((address_space(3))) void*)l, 16, 0, 0);
}

// ---------------------------------------------------------------- prep_w ----
// grid (16, 3): transpose one 64k x 128n slab of W_w via LDS, coalesced both ways.
__global__ __launch_bounds__(256) void prep_w_kernel(
    const float* __restrict__ wk, const float* __restrict__ wq,
    const float* __restrict__ wv, u16* __restrict__ Wt) {
  __shared__ u16 L[64 * 136];
  const int w = blockIdx.y;
  const int k0 = blockIdx.x * 64;
  const float* W = (w == 0) ? wk : (w == 1) ? wq : wv;
  const int t = threadIdx.x;
#pragma unroll
  for (int p = 0; p < 8; ++p) {
    int idx = p * 256 + t;
    int k = idx >> 5, c4 = (idx & 31) * 4;
    float4 v = *(const float4*)&W[(size_t)(k0 + k) * H_DIM + c4];
    u16x4 bv;
    bv.x = f2bf(v.x); bv.y = f2bf(v.y); bv.z = f2bf(v.z); bv.w = f2bf(v.w);
    *(u16x4*)&L[k * 136 + c4] = bv;
  }
  __syncthreads();
#pragma unroll
  for (int p = 0; p < 4; ++p) {
    int cid = p * 256 + t;
    int n = cid >> 3, kc = (cid & 7) * 8;
    u16x8 o;
#pragma unroll
    for (int j = 0; j < 8; ++j) o[j] = L[(kc + j) * 136 + n];
    *(u16x8*)&Wt[(size_t)w * 131072 + (size_t)n * 1024 + k0 + kc] = o;
  }
}

// ------------------------------------------------------------------ proj ----
// 256 blocks x 64 rows, 4 waves all computing (wave owns cols384
// wave*96 + j*16 + lq, j=0..5). W staged via global_load_lds into
// Wl[384][64] (XOR-swizzled chunks); x staged via regs (needs f32->bf16).
__global__ __launch_bounds__(256, 1) void proj_kernel(
    const float* __restrict__ x, const u16* __restrict__ Wt,
    u16* __restrict__ Qb, u16* __restrict__ Kb, u16* __restrict__ Vt) {
  __shared__ __attribute__((aligned(16))) u16 smem[64 * 72 + 384 * 64];
  u16* Xl = smem;            // [64][64] pad 72
  u16* Wl = smem + 64 * 72;  // [384][64] linear, XOR-swizzled 16B chunks
  const int m0 = blockIdx.x * 64;
  const int t = threadIdx.x;
  const int wave = t >> 6, lane = t & 63;
  const int g = lane >> 4, lq = lane & 15;
  const int lsw = lq & 7;

  f32x4 acc[4][6] = {};

  for (int k0 = 0; k0 < C_DIM; k0 += 64) {
    __syncthreads();
#pragma unroll
    for (int p = 0; p < 4; ++p) {  // stage x: 64x64 f32 -> bf16 (reg path)
      int idx = p * 256 + t;
      int row = idx >> 4, c4 = (idx & 15) * 4;
      float4 v = *(const float4*)&x[(size_t)(m0 + row) * C_DIM + k0 + c4];
      u16x4 bv;
      bv.x = f2bf(v.x); bv.y = f2bf(v.y); bv.z = f2bf(v.z); bv.w = f2bf(v.w);
      *(u16x4*)&Xl[row * 72 + c4] = bv;
    }
    // stage Wt 384x64 via global_load_lds: issue p covers 8 rows (1KB).
    // lane l -> row r0+(l>>3), phys chunk l&7 sourcing logical (l&7)^(l>>3).
#pragma unroll
    for (int p = 0; p < 12; ++p) {
      int r0 = (wave * 12 + p) * 8;
      int r = r0 + (lane >> 3);
      int csrc = (lane & 7) ^ (lane >> 3);
      gll16(&Wt[(size_t)(r >> 7) * 131072 + (size_t)(r & 127) * 1024 + k0 +
                csrc * 8],
            &Wl[r0 * 64]);
    }
    __syncthreads();
#pragma unroll
    for (int kk = 0; kk < 2; ++kk) {
      u16x8 af[4], bfr[6];
#pragma unroll
      for (int i = 0; i < 4; ++i)
        af[i] = *(const u16x8*)&Xl[(i * 16 + lq) * 72 + kk * 32 + g * 8];
#pragma unroll
      for (int j = 0; j < 6; ++j)
        bfr[j] = *(const u16x8*)&Wl[(wave * 96 + j * 16 + lq) * 64 +
                                    (((kk * 4 + g) ^ lsw) * 8)];
#pragma unroll
      for (int i = 0; i < 4; ++i)
#pragma unroll
        for (int j = 0; j < 6; ++j)
          acc[i][j] = mfma16x16(af[i], bfr[j], acc[i][j]);
    }
  }

  const float qscale = 0.08838834764831845f;  // 128^-0.5
#pragma unroll
  for (int j = 0; j < 6; ++j) {  // K and Q direct writes (wave-uniform branch)
    const int c384 = wave * 96 + j * 16;
    const int which = c384 >> 7;
    const int col = (c384 & 127) + lq;
    if (which == 0) {
#pragma unroll
      for (int i = 0; i < 4; ++i)
#pragma unroll
        for (int r = 0; r < 4; ++r)
          Kb[(size_t)(m0 + i * 16 + g * 4 + r) * H_DIM + col] =
              f2bf(acc[i][j][r]);
    } else if (which == 1) {
#pragma unroll
      for (int i = 0; i < 4; ++i)
#pragma unroll
        for (int r = 0; r < 4; ++r)
          Qb[(size_t)(m0 + i * 16 + g * 4 + r) * H_DIM + col] =
              f2bf(acc[i][j][r] * qscale);
    }
  }
  __syncthreads();
#pragma unroll
  for (int j = 0; j < 6; ++j) {  // V -> LDS transposed [128 h][64 m] pad 72
    const int c384 = wave * 96 + j * 16;
    if ((c384 >> 7) == 2) {
      const int v = (c384 & 127) + lq;
#pragma unroll
      for (int i = 0; i < 4; ++i)
#pragma unroll
        for (int r = 0; r < 4; ++r)
          smem[v * 72 + i * 16 + g * 4 + r] = f2bf(acc[i][j][r]);
    }
  }
  __syncthreads();
  {
    const int b = m0 >> 12;
    const int t0 = m0 & 4095;
#pragma unroll
    for (int p = 0; p < 4; ++p) {
      int idx = p * 256 + t;
      int h = idx >> 3, mc = (idx & 7) * 8;
      *(u16x8*)&Vt[(size_t)b * (H_DIM * T_DIM) + (size_t)h * T_DIM + t0 + mc] =
          *(const u16x8*)&smem[h * 72 + mc];
    }
  }
}

// ------------------------------------------------------------------ attn ----
// 512 threads: 8 waves x 16 q-rows = QBLK 128 sharing one K/V staging via
// global_load_lds (pre-swizzled source; LDS phys chunk p of row r holds
// logical chunk p^(r&7); reads identical to R8). launch_bounds(512,4).
// split: 1088 blocks, XCD-pinned batch, heavy entries first, chunk=256.
__global__ __launch_bounds__(512, 4) void attn_kernel(
    const u16* __restrict__ Qb, const u16* __restrict__ Kb,
    const u16* __restrict__ Vt, float* __restrict__ out,
    u16* __restrict__ Opart, float* __restrict__ ml, int split) {
  __shared__ __attribute__((aligned(16))) u16 Kl[64 * 128];  // swizzled
  __shared__ __attribute__((aligned(16))) u16 Vl[128 * 64];  // swizzled
  __shared__ __attribute__((aligned(16))) u16 Pl[8][16 * 72];
  const int t = threadIdx.x;
  const int wave = t >> 6, lane = t & 63;
  const int g = lane >> 4, lq = lane & 15;
  const int lsw = lane & 7;  // read-side swizzle key (= row&7 for row=16nf+lq)

  int b, qb, kvb, kve, pid;
  if (split) {
    int bid = (int)blockIdx.x;  // 1088 linear
    int xcd = bid & 7;
    b = xcd >> 1;  // batch pinned to an XCD pair -> K/V L2-local
    int e = (EPB - 1) - ((bid >> 3) * 2 + (bid & 1));  // heavy-first
    int a = 0;
#pragma unroll
    for (int c = 1; c <= 15; ++c)
      if (e >= c * (c + 1)) a = c;
    int off = e - a * (a + 1);
    int d = off / (a + 1);
    int ch = off - d * (a + 1);
    qb = 2 * a + d;
    kvb = ch * 256;
    pid = b * EPB + e;
    int kv_full = qb * 128 + 128;
    kve = (kvb + 256 < kv_full) ? kvb + 256 : kv_full;
  } else {
    b = (int)blockIdx.x & 3;
    qb = 31 - ((int)blockIdx.x >> 2);
    kvb = 0;
    kve = qb * 128 + 128;
    pid = 0;
  }
  const int rowq = qb * 128 + wave * 16;  // wave's first q-row

  u16x8 qf[4];  // 16 q-rows x 128, A-frag layout (prescaled)
  {
    const u16* Qp = Qb + (size_t)(b * T_DIM + rowq + lq) * H_DIM;
#pragma unroll
    for (int c = 0; c < 4; ++c) qf[c] = *(const u16x8*)&Qp[c * 32 + g * 8];
  }

  f32x4 ao[8] = {};
  float m_run[4], l_run[4];
#pragma unroll
  for (int r = 0; r < 4; ++r) { m_run[r] = -INFINITY; l_run[r] = 0.f; }

  const u16* Kg0 = Kb + (size_t)b * T_DIM * H_DIM;
  const u16* Vg0 = Vt + (size_t)b * H_DIM * T_DIM;

  for (int kv0 = kvb; kv0 < kve; kv0 += 64) {
    __syncthreads();
    // K tile [64][128]: 2 issues/wave, each 4 rows (1KB). lane l -> row
    // r0+(l>>4), phys chunk l&15, source logical chunk (l&15)^(r&7).
#pragma unroll
    for (int i = 0; i < 2; ++i) {
      int r0 = (i * 8 + wave) * 4;
      int r = r0 + (lane >> 4);
      int csrc = (lane & 15) ^ (r & 7);
      gll16(&Kg0[(size_t)(kv0 + r) * H_DIM + csrc * 8], &Kl[r0 * 128]);
    }
    // V tile [128][64]: 2 issues/wave, each 8 rows (1KB). lane l -> row
    // h0+(l>>3), phys chunk l&7, source logical chunk (l&7)^(h&7).
#pragma unroll
    for (int i = 0; i < 2; ++i) {
      int h0 = (i * 8 + wave) * 8;
      int h = h0 + (lane >> 3);
      int csrc = (lane & 7) ^ (lane >> 3);
      gll16(&Vg0[(size_t)h * T_DIM + kv0 + csrc * 8], &Vl[h0 * 64]);
    }
    __syncthreads();

    if (kv0 > rowq + 15) continue;  // fully masked for this wave (uniform)

    // S = Q K^T (Q prescaled): 4 col-frags x 4 k-chunks from swizzled LDS
    f32x4 s[4];
#pragma unroll
    for (int nf = 0; nf < 4; ++nf) s[nf] = f32x4{0.f, 0.f, 0.f, 0.f};
#pragma unroll
    for (int nf = 0; nf < 4; ++nf)
#pragma unroll
      for (int c = 0; c < 4; ++c) {
        u16x8 kf = *(const u16x8*)&Kl[(nf * 16 + lq) * 128 +
                                      (((c * 4 + g) ^ lsw) * 8)];
        s[nf] = mfma16x16(qf[c], kf, s[nf]);
      }

    if (kv0 + 63 > rowq) {  // diagonal overlap: elementwise causal mask
      int row = rowq + g * 4;
#pragma unroll
      for (int nf = 0; nf < 4; ++nf) {
        int col = kv0 + nf * 16 + lq;
#pragma unroll
        for (int r = 0; r < 4; ++r)
          if (col > row + r) s[nf][r] = -INFINITY;
      }
    }

    // online softmax; rows 4g..4g+3 live in 16-lane group g
    float mloc[4];
#pragma unroll
    for (int r = 0; r < 4; ++r)
      mloc[r] = fmaxf(fmaxf(s[0][r], s[1][r]), fmaxf(s[2][r], s[3][r]));
#pragma unroll
    for (int off = 1; off < 16; off <<= 1)
#pragma unroll
      for (int r = 0; r < 4; ++r)
        mloc[r] = fmaxf(mloc[r], __shfl_xor(mloc[r], off));

    float al[4], ps[4];
#pragma unroll
    for (int r = 0; r < 4; ++r) {
      float mn = fmaxf(m_run[r], mloc[r]);
      al[r] = __expf(m_run[r] - mn);
      m_run[r] = mn;
      ps[r] = 0.f;
    }
#pragma unroll
    for (int nf = 0; nf < 4; ++nf)
#pragma unroll
      for (int r = 0; r < 4; ++r) {
        float p = __expf(s[nf][r] - m_run[r]);
        s[nf][r] = p;
        ps[r] += p;
      }
#pragma unroll
    for (int off = 1; off < 16; off <<= 1)
#pragma unroll
      for (int r = 0; r < 4; ++r) ps[r] += __shfl_xor(ps[r], off);
#pragma unroll
    for (int r = 0; r < 4; ++r) l_run[r] = l_run[r] * al[r] + ps[r];

    // defer-rescale: skip O-wide pass when max unchanged (wave-uniform)
    bool nochg = (al[0] == 1.f) && (al[1] == 1.f) && (al[2] == 1.f) &&
                 (al[3] == 1.f);
    if (!__all(nochg)) {
#pragma unroll
      for (int h8 = 0; h8 < 8; ++h8)
#pragma unroll
        for (int r = 0; r < 4; ++r) ao[h8][r] *= al[r];
    }

    // P (D-layout) -> per-wave LDS -> A-layout frags
#pragma unroll
    for (int nf = 0; nf < 4; ++nf)
#pragma unroll
      for (int r = 0; r < 4; ++r)
        Pl[wave][(g * 4 + r) * 72 + nf * 16 + lq] = f2bf(s[nf][r]);

    u16x8 pf[2];
#pragma unroll
    for (int kk = 0; kk < 2; ++kk)
      pf[kk] = *(const u16x8*)&Pl[wave][lq * 72 + kk * 32 + g * 8];
#pragma unroll
    for (int h8 = 0; h8 < 8; ++h8)
#pragma unroll
      for (int kk = 0; kk < 2; ++kk) {
        u16x8 vf = *(const u16x8*)&Vl[(h8 * 16 + lq) * 64 +
                                      (((kk * 4 + g) ^ lsw) * 8)];
        ao[h8] = mfma16x16(pf[kk], vf, ao[h8]);
      }
  }

  if (!split) {
    float inv[4];
#pragma unroll
    for (int r = 0; r < 4; ++r) inv[r] = 1.f / l_run[r];
    float* Og = out + (size_t)(b * T_DIM + rowq) * H_DIM;
#pragma unroll
    for (int h8 = 0; h8 < 8; ++h8)
#pragma unroll
      for (int r = 0; r < 4; ++r)
        Og[(size_t)(g * 4 + r) * H_DIM + h8 * 16 + lq] = ao[h8][r] * inv[r];
  } else {
    u16* Op = Opart + (size_t)pid * 16384 + (size_t)(wave * 16) * H_DIM;
#pragma unroll
    for (int h8 = 0; h8 < 8; ++h8)
#pragma unroll
      for (int r = 0; r < 4; ++r)
        Op[(g * 4 + r) * H_DIM + h8 * 16 + lq] = f2bf(ao[h8][r]);
    if (lq == 0) {
      float* mlp = ml + (size_t)pid * 256;
#pragma unroll
      for (int r = 0; r < 4; ++r) {
        int row = wave * 16 + g * 4 + r;
        mlp[row] = m_run[r];
        mlp[128 + row] = l_run[r];
      }
    }
  }
}

// --------------------------------------------------------------- combine ----
// grid (128, 4): 512 blocks; each merges 32 rows of a 128-row q-block
// (<=16 bf16 partials), 16 accumulators/thread.
__global__ __launch_bounds__(256) void combine_kernel(
    const u16* __restrict__ Opart, const float* __restrict__ ml,
    float* __restrict__ out) {
  const int blk = blockIdx.x;
  const int qb = blk >> 2;
  const int sub = blk & 3;
  const int b = blockIdx.y;
  const int t = threadIdx.x;
  const int row = sub * 32 + (t >> 3);  // row within the 128-row q-block
  const int colb = (t & 7) * 16;
  const int a = qb >> 1;
  const int n = a + 1;
  const int base = a * (a + 1) + (qb & 1) * (a + 1);
  const int pid0 = b * EPB + base;

  float M = -INFINITY;
  for (int i = 0; i < n; ++i)
    M = fmaxf(M, ml[(size_t)(pid0 + i) * 256 + row]);

  float L = 0.f;
  float o[16] = {};
  for (int i = 0; i < n; ++i) {
    const size_t mb = (size_t)(pid0 + i) * 256;
    float sc = __expf(ml[mb + row] - M);
    L += sc * ml[mb + 128 + row];
    const u16* Op = Opart + (size_t)(pid0 + i) * 16384 + row * H_DIM + colb;
#pragma unroll
    for (int p = 0; p < 2; ++p) {
      u16x8 v = *(const u16x8*)&Op[p * 8];
#pragma unroll
      for (int e = 0; e < 8; ++e) o[p * 8 + e] += sc * bf2f(v[e]);
    }
  }
  float inv = 1.f / L;
  float* Og = out + ((size_t)b * T_DIM + qb * 128 + row) * H_DIM + colb;
#pragma unroll
  for (int p = 0; p < 4; ++p) {
    f32x4 v = {o[p * 4] * inv, o[p * 4 + 1] * inv, o[p * 4 + 2] * inv,
               o[p * 4 + 3] * inv};
    *(f32x4*)&Og[p * 4] = v;
  }
}

// ---------------------------------------------------------------- launch ----
extern "C" void kernel_launch(void* const* d_in, const int* in_sizes, int n_in,
                              void* d_out, int out_size, void* d_ws,
                              size_t ws_size, hipStream_t stream) {
  const float* x = (const float*)d_in[0];
  const float* wk = (const float*)d_in[1];
  const float* wq = (const float*)d_in[2];
  const float* wv = (const float*)d_in[3];
  float* out = (float*)d_out;
  char* ws = (char*)d_ws;

  u16* Wt = (u16*)ws;
  u16* Qb = (u16*)(ws + 786432);
  u16* Kb = (u16*)(ws + 786432 + 4194304);
  u16* Vt = (u16*)(ws + 786432 + 8388608);
  u16* Opart = (u16*)(ws + 13369344);
  float* ml = (float*)(ws + 49020928);

  const int split = (ws_size >= WS_SPLIT_NEED) ? 1 : 0;

  prep_w_kernel<<<dim3(16, 3), 256, 0, stream>>>(wk, wq, wv, Wt);
  proj_kernel<<<256, 256, 0, stream>>>(x, Wt, Qb, Kb, Vt);
  if (split) {
    attn_kernel<<<4 * EPB, 512, 0, stream>>>(Qb, Kb, Vt, out, Opart, ml, 1);
    combine_kernel<<<dim3(128, 4), 256, 0, stream>>>(Opart, ml, out);
  } else {
    attn_kernel<<<128, 512, 0, stream>>>(Qb, Kb, Vt, out, Opart, ml, 0);
  }
}

// Round 10
// 92.437 us; speedup vs baseline: 1.7207x; 1.1003x over previous
//
#include <hip/hip_runtime.h>
#include <hip/hip_bf16.h>

// Single-head causal self-attention, B=4 T=4096 C=1024 H=128, f32 in/out.
// prep_w: W -> Wt bf16 [3][128][1024] n-major, via LDS transpose (coalesced)
// proj:   fused x@{Wk,Wq,Wv}, 256-thr blocks; W staged via global_load_lds
//         (async, pre-swizzled source, linear LDS); Q prescaled; V transposed.
// attn:   flash causal, 512-thr: QBLK=128 = 8 waves x 16 q-rows, K/V staged
//         via global_load_lds into XOR-swizzled LDS. SWAPPED QK^T: lane holds
//         one q-row's 16 S-values -> softmax is in-lane tree + 2 shfl (no
//         32-bpermute butterflies). kv-split chunk=256, heavy-first,
//         XCD-pinned batch. Partials bf16.
// combine: grid (128,4): 32 rows/block, <=16 partials, 16 acc/thread.
//
// ws map (bytes):
//   Wt    [0,        786432)
//   Qb    [786432,   +4MB)
//   Kb    [+4MB)
//   Vt    [+4MB)                      -> 13369344
//   Opart [13369344, +1088*32KB)      -> 49020928   (bf16)
//   ml    [49020928, +1114112)        -> 50135040

typedef unsigned short u16;
typedef __attribute__((ext_vector_type(8))) __bf16 bf16x8;
typedef __attribute__((ext_vector_type(8))) u16 u16x8;
typedef __attribute__((ext_vector_type(4))) u16 u16x4;
typedef __attribute__((ext_vector_type(4))) float f32x4;

#define T_DIM 4096
#define C_DIM 1024
#define H_DIM 128
#define EPB 272  // entries per batch: sum_{qb<32} ceil((qb+1)/2), chunk=256
#define WS_SPLIT_NEED 50135040ull

static __device__ __forceinline__ f32x4 mfma16x16(u16x8 a, u16x8 b, f32x4 c) {
  return __builtin_amdgcn_mfma_f32_16x16x32_bf16(
      __builtin_bit_cast(bf16x8, a), __builtin_bit_cast(bf16x8, b), c, 0, 0, 0);
}

static __device__ __forceinline__ u16 f2bf(float f) {
  __hip_bfloat16 h = __float2bfloat16(f);
  return __builtin_bit_cast(u16, h);
}

static __device__ __forceinline__ float bf2f(u16 u) {
  unsigned x = (unsigned)u << 16;
  return __builtin_bit_cast(float, x);
}

// async global->LDS, 16B per lane; lptr must be wave-uniform base.
static __device__ __forceinline__ void gll16(const u16* g, u16* l) {
  __builtin_amdgcn_global_load_lds(
      (const __attribute__((address_space(1))) void*)(void*)g,
      (__attribute__((address_space(3))) void*)l, 16, 0, 0);
}

// ---------------------------------------------------------------- prep_w ----
// grid (16, 3): transpose one 64k x 128n slab of W_w via LDS, coalesced both ways.
__global__ __launch_bounds__(256) void prep_w_kernel(
    const float* __restrict__ wk, const float* __restrict__ wq,
    const float* __restrict__ wv, u16* __restrict__ Wt) {
  __shared__ u16 L[64 * 136];
  const int w = blockIdx.y;
  const int k0 = blockIdx.x * 64;
  const float* W = (w == 0) ? wk : (w == 1) ? wq : wv;
  const int t = threadIdx.x;
#pragma unroll
  for (int p = 0; p < 8; ++p) {
    int idx = p * 256 + t;
    int k = idx >> 5, c4 = (idx & 31) * 4;
    float4 v = *(const float4*)&W[(size_t)(k0 + k) * H_DIM + c4];
    u16x4 bv;
    bv.x = f2bf(v.x); bv.y = f2bf(v.y); bv.z = f2bf(v.z); bv.w = f2bf(v.w);
    *(u16x4*)&L[k * 136 + c4] = bv;
  }
  __syncthreads();
#pragma unroll
  for (int p = 0; p < 4; ++p) {
    int cid = p * 256 + t;
    int n = cid >> 3, kc = (cid & 7) * 8;
    u16x8 o;
#pragma unroll
    for (int j = 0; j < 8; ++j) o[j] = L[(kc + j) * 136 + n];
    *(u16x8*)&Wt[(size_t)w * 131072 + (size_t)n * 1024 + k0 + kc] = o;
  }
}

// ------------------------------------------------------------------ proj ----
// 256 blocks x 64 rows, 4 waves all computing (wave owns cols384
// wave*96 + j*16 + lq, j=0..5). W staged via global_load_lds into
// Wl[384][64] (XOR-swizzled chunks); x staged via regs (needs f32->bf16).
__global__ __launch_bounds__(256, 1) void proj_kernel(
    const float* __restrict__ x, const u16* __restrict__ Wt,
    u16* __restrict__ Qb, u16* __restrict__ Kb, u16* __restrict__ Vt) {
  __shared__ __attribute__((aligned(16))) u16 smem[64 * 72 + 384 * 64];
  u16* Xl = smem;            // [64][64] pad 72
  u16* Wl = smem + 64 * 72;  // [384][64] linear, XOR-swizzled 16B chunks
  const int m0 = blockIdx.x * 64;
  const int t = threadIdx.x;
  const int wave = t >> 6, lane = t & 63;
  const int g = lane >> 4, lq = lane & 15;
  const int lsw = lq & 7;

  f32x4 acc[4][6] = {};

  for (int k0 = 0; k0 < C_DIM; k0 += 64) {
    __syncthreads();
#pragma unroll
    for (int p = 0; p < 4; ++p) {  // stage x: 64x64 f32 -> bf16 (reg path)
      int idx = p * 256 + t;
      int row = idx >> 4, c4 = (idx & 15) * 4;
      float4 v = *(const float4*)&x[(size_t)(m0 + row) * C_DIM + k0 + c4];
      u16x4 bv;
      bv.x = f2bf(v.x); bv.y = f2bf(v.y); bv.z = f2bf(v.z); bv.w = f2bf(v.w);
      *(u16x4*)&Xl[row * 72 + c4] = bv;
    }
    // stage Wt 384x64 via global_load_lds: issue p covers 8 rows (1KB).
#pragma unroll
    for (int p = 0; p < 12; ++p) {
      int r0 = (wave * 12 + p) * 8;
      int r = r0 + (lane >> 3);
      int csrc = (lane & 7) ^ (lane >> 3);
      gll16(&Wt[(size_t)(r >> 7) * 131072 + (size_t)(r & 127) * 1024 + k0 +
                csrc * 8],
            &Wl[r0 * 64]);
    }
    __syncthreads();
#pragma unroll
    for (int kk = 0; kk < 2; ++kk) {
      u16x8 af[4], bfr[6];
#pragma unroll
      for (int i = 0; i < 4; ++i)
        af[i] = *(const u16x8*)&Xl[(i * 16 + lq) * 72 + kk * 32 + g * 8];
#pragma unroll
      for (int j = 0; j < 6; ++j)
        bfr[j] = *(const u16x8*)&Wl[(wave * 96 + j * 16 + lq) * 64 +
                                    (((kk * 4 + g) ^ lsw) * 8)];
#pragma unroll
      for (int i = 0; i < 4; ++i)
#pragma unroll
        for (int j = 0; j < 6; ++j)
          acc[i][j] = mfma16x16(af[i], bfr[j], acc[i][j]);
    }
  }

  const float qscale = 0.08838834764831845f;  // 128^-0.5
#pragma unroll
  for (int j = 0; j < 6; ++j) {  // K and Q direct writes (wave-uniform branch)
    const int c384 = wave * 96 + j * 16;
    const int which = c384 >> 7;
    const int col = (c384 & 127) + lq;
    if (which == 0) {
#pragma unroll
      for (int i = 0; i < 4; ++i)
#pragma unroll
        for (int r = 0; r < 4; ++r)
          Kb[(size_t)(m0 + i * 16 + g * 4 + r) * H_DIM + col] =
              f2bf(acc[i][j][r]);
    } else if (which == 1) {
#pragma unroll
      for (int i = 0; i < 4; ++i)
#pragma unroll
        for (int r = 0; r < 4; ++r)
          Qb[(size_t)(m0 + i * 16 + g * 4 + r) * H_DIM + col] =
              f2bf(acc[i][j][r] * qscale);
    }
  }
  __syncthreads();
#pragma unroll
  for (int j = 0; j < 6; ++j) {  // V -> LDS transposed [128 h][64 m] pad 72
    const int c384 = wave * 96 + j * 16;
    if ((c384 >> 7) == 2) {
      const int v = (c384 & 127) + lq;
#pragma unroll
      for (int i = 0; i < 4; ++i)
#pragma unroll
        for (int r = 0; r < 4; ++r)
          smem[v * 72 + i * 16 + g * 4 + r] = f2bf(acc[i][j][r]);
    }
  }
  __syncthreads();
  {
    const int b = m0 >> 12;
    const int t0 = m0 & 4095;
#pragma unroll
    for (int p = 0; p < 4; ++p) {
      int idx = p * 256 + t;
      int h = idx >> 3, mc = (idx & 7) * 8;
      *(u16x8*)&Vt[(size_t)b * (H_DIM * T_DIM) + (size_t)h * T_DIM + t0 + mc] =
          *(const u16x8*)&smem[h * 72 + mc];
    }
  }
}

// ------------------------------------------------------------------ attn ----
// 512 threads: 8 waves x 16 q-rows = QBLK 128 sharing one K/V staging via
// global_load_lds (pre-swizzled source). SWAPPED QK^T: s = mfma(K,Q) puts a
// full q-row (16 S values) in each lane -> in-lane softmax tree + 2 shfl.
// split: 1088 blocks, XCD-pinned batch, heavy entries first, chunk=256.
__global__ __launch_bounds__(512, 4) void attn_kernel(
    const u16* __restrict__ Qb, const u16* __restrict__ Kb,
    const u16* __restrict__ Vt, float* __restrict__ out,
    u16* __restrict__ Opart, float* __restrict__ ml, int split) {
  __shared__ __attribute__((aligned(16))) u16 Kl[64 * 128];  // swizzled
  __shared__ __attribute__((aligned(16))) u16 Vl[128 * 64];  // swizzled
  __shared__ __attribute__((aligned(16))) u16 Pl[8][16 * 72];
  const int t = threadIdx.x;
  const int wave = t >> 6, lane = t & 63;
  const int g = lane >> 4, lq = lane & 15;
  const int lsw = lane & 7;  // read-side swizzle key (= row&7 for row=16nf+lq)

  int b, qb, kvb, kve, pid;
  if (split) {
    int bid = (int)blockIdx.x;  // 1088 linear
    int xcd = bid & 7;
    b = xcd >> 1;  // batch pinned to an XCD pair -> K/V L2-local
    int e = (EPB - 1) - ((bid >> 3) * 2 + (bid & 1));  // heavy-first
    int a = 0;
#pragma unroll
    for (int c = 1; c <= 15; ++c)
      if (e >= c * (c + 1)) a = c;
    int off = e - a * (a + 1);
    int d = off / (a + 1);
    int ch = off - d * (a + 1);
    qb = 2 * a + d;
    kvb = ch * 256;
    pid = b * EPB + e;
    int kv_full = qb * 128 + 128;
    kve = (kvb + 256 < kv_full) ? kvb + 256 : kv_full;
  } else {
    b = (int)blockIdx.x & 3;
    qb = 31 - ((int)blockIdx.x >> 2);
    kvb = 0;
    kve = qb * 128 + 128;
    pid = 0;
  }
  const int rowq = qb * 128 + wave * 16;  // wave's first q-row
  const int qrow = rowq + lq;             // this lane's q row (swapped layout)

  u16x8 qf[4];  // 16 q-rows x 128, A-frag layout (prescaled)
  {
    const u16* Qp = Qb + (size_t)(b * T_DIM + qrow) * H_DIM;
#pragma unroll
    for (int c = 0; c < 4; ++c) qf[c] = *(const u16x8*)&Qp[c * 32 + g * 8];
  }

  f32x4 ao[8] = {};
  float m_run = -INFINITY, l_run = 0.f;  // per-lane scalars (q = qrow)

  const u16* Kg0 = Kb + (size_t)b * T_DIM * H_DIM;
  const u16* Vg0 = Vt + (size_t)b * H_DIM * T_DIM;

  for (int kv0 = kvb; kv0 < kve; kv0 += 64) {
    __syncthreads();
    // K tile [64][128]: 2 issues/wave, each 4 rows (1KB).
#pragma unroll
    for (int i = 0; i < 2; ++i) {
      int r0 = (i * 8 + wave) * 4;
      int r = r0 + (lane >> 4);
      int csrc = (lane & 15) ^ (r & 7);
      gll16(&Kg0[(size_t)(kv0 + r) * H_DIM + csrc * 8], &Kl[r0 * 128]);
    }
    // V tile [128][64]: 2 issues/wave, each 8 rows (1KB).
#pragma unroll
    for (int i = 0; i < 2; ++i) {
      int h0 = (i * 8 + wave) * 8;
      int h = h0 + (lane >> 3);
      int csrc = (lane & 7) ^ (lane >> 3);
      gll16(&Vg0[(size_t)h * T_DIM + kv0 + csrc * 8], &Vl[h0 * 64]);
    }
    __syncthreads();

    if (kv0 > rowq + 15) continue;  // fully masked for this wave (uniform)

    // S^T = mfma(K, Q): lane (g,lq) holds S[qrow][kv0 + nf*16 + 4g + r]
    f32x4 s[4];
#pragma unroll
    for (int nf = 0; nf < 4; ++nf) s[nf] = f32x4{0.f, 0.f, 0.f, 0.f};
#pragma unroll
    for (int nf = 0; nf < 4; ++nf)
#pragma unroll
      for (int c = 0; c < 4; ++c) {
        u16x8 kf = *(const u16x8*)&Kl[(nf * 16 + lq) * 128 +
                                      (((c * 4 + g) ^ lsw) * 8)];
        s[nf] = mfma16x16(kf, qf[c], s[nf]);
      }

    if (kv0 + 63 > rowq) {  // diagonal overlap: elementwise causal mask
      const int kb = kv0 + g * 4;
#pragma unroll
      for (int nf = 0; nf < 4; ++nf)
#pragma unroll
        for (int r = 0; r < 4; ++r)
          if (kb + nf * 16 + r > qrow) s[nf][r] = -INFINITY;
    }

    // softmax: in-lane tree over 16 values + cross-g (xor 16, 32)
    float t0 = fmaxf(fmaxf(s[0][0], s[0][1]), fmaxf(s[0][2], s[0][3]));
    float t1 = fmaxf(fmaxf(s[1][0], s[1][1]), fmaxf(s[1][2], s[1][3]));
    float t2 = fmaxf(fmaxf(s[2][0], s[2][1]), fmaxf(s[2][2], s[2][3]));
    float t3 = fmaxf(fmaxf(s[3][0], s[3][1]), fmaxf(s[3][2], s[3][3]));
    float pmax = fmaxf(fmaxf(t0, t1), fmaxf(t2, t3));
    pmax = fmaxf(pmax, __shfl_xor(pmax, 16));
    pmax = fmaxf(pmax, __shfl_xor(pmax, 32));

    float mn = fmaxf(m_run, pmax);
    float al = __expf(m_run - mn);
    m_run = mn;
#pragma unroll
    for (int nf = 0; nf < 4; ++nf)
#pragma unroll
      for (int r = 0; r < 4; ++r) s[nf][r] = __expf(s[nf][r] - mn);
    float u0 = (s[0][0] + s[0][1]) + (s[0][2] + s[0][3]);
    float u1 = (s[1][0] + s[1][1]) + (s[1][2] + s[1][3]);
    float u2 = (s[2][0] + s[2][1]) + (s[2][2] + s[2][3]);
    float u3 = (s[3][0] + s[3][1]) + (s[3][2] + s[3][3]);
    float ps = (u0 + u1) + (u2 + u3);
    ps += __shfl_xor(ps, 16);
    ps += __shfl_xor(ps, 32);
    l_run = l_run * al + ps;

    // defer-rescale: only broadcast+rescale when some row's max moved
    if (!__all(al == 1.f)) {
      float alr[4];
#pragma unroll
      for (int r = 0; r < 4; ++r) alr[r] = __shfl(al, g * 4 + r);
#pragma unroll
      for (int h8 = 0; h8 < 8; ++h8)
#pragma unroll
        for (int r = 0; r < 4; ++r) ao[h8][r] *= alr[r];
    }

    // P (swapped layout) -> per-wave LDS [q=row][k=col] -> A-frags
#pragma unroll
    for (int nf = 0; nf < 4; ++nf)
#pragma unroll
      for (int r = 0; r < 4; ++r)
        Pl[wave][lq * 72 + nf * 16 + g * 4 + r] = f2bf(s[nf][r]);

    u16x8 pf[2];
#pragma unroll
    for (int kk = 0; kk < 2; ++kk)
      pf[kk] = *(const u16x8*)&Pl[wave][lq * 72 + kk * 32 + g * 8];
#pragma unroll
    for (int h8 = 0; h8 < 8; ++h8)
#pragma unroll
      for (int kk = 0; kk < 2; ++kk) {
        u16x8 vf = *(const u16x8*)&Vl[(h8 * 16 + lq) * 64 +
                                      (((kk * 4 + g) ^ lsw) * 8)];
        ao[h8] = mfma16x16(pf[kk], vf, ao[h8]);
      }
  }

  if (!split) {
    float linv = 1.f / l_run;
    float inv[4];
#pragma unroll
    for (int r = 0; r < 4; ++r) inv[r] = __shfl(linv, g * 4 + r);
    float* Og = out + (size_t)(b * T_DIM + rowq) * H_DIM;
#pragma unroll
    for (int h8 = 0; h8 < 8; ++h8)
#pragma unroll
      for (int r = 0; r < 4; ++r)
        Og[(size_t)(g * 4 + r) * H_DIM + h8 * 16 + lq] = ao[h8][r] * inv[r];
  } else {
    u16* Op = Opart + (size_t)pid * 16384 + (size_t)(wave * 16) * H_DIM;
#pragma unroll
    for (int h8 = 0; h8 < 8; ++h8)
#pragma unroll
      for (int r = 0; r < 4; ++r)
        Op[(g * 4 + r) * H_DIM + h8 * 16 + lq] = f2bf(ao[h8][r]);
    if (lane < 16) {  // lane lq holds m/l for q-local row wave*16+lq
      float* mlp = ml + (size_t)pid * 256;
      mlp[wave * 16 + lane] = m_run;
      mlp[128 + wave * 16 + lane] = l_run;
    }
  }
}

// --------------------------------------------------------------- combine ----
// grid (128, 4): 512 blocks; each merges 32 rows of a 128-row q-block
// (<=16 bf16 partials), 16 accumulators/thread.
__global__ __launch_bounds__(256) void combine_kernel(
    const u16* __restrict__ Opart, const float* __restrict__ ml,
    float* __restrict__ out) {
  const int blk = blockIdx.x;
  const int qb = blk >> 2;
  const int sub = blk & 3;
  const int b = blockIdx.y;
  const int t = threadIdx.x;
  const int row = sub * 32 + (t >> 3);  // row within the 128-row q-block
  const int colb = (t & 7) * 16;
  const int a = qb >> 1;
  const int n = a + 1;
  const int base = a * (a + 1) + (qb & 1) * (a + 1);
  const int pid0 = b * EPB + base;

  float M = -INFINITY;
  for (int i = 0; i < n; ++i)
    M = fmaxf(M, ml[(size_t)(pid0 + i) * 256 + row]);

  float L = 0.f;
  float o[16] = {};
  for (int i = 0; i < n; ++i) {
    const size_t mb = (size_t)(pid0 + i) * 256;
    float sc = __expf(ml[mb + row] - M);
    L += sc * ml[mb + 128 + row];
    const u16* Op = Opart + (size_t)(pid0 + i) * 16384 + row * H_DIM + colb;
#pragma unroll
    for (int p = 0; p < 2; ++p) {
      u16x8 v = *(const u16x8*)&Op[p * 8];
#pragma unroll
      for (int e = 0; e < 8; ++e) o[p * 8 + e] += sc * bf2f(v[e]);
    }
  }
  float inv = 1.f / L;
  float* Og = out + ((size_t)b * T_DIM + qb * 128 + row) * H_DIM + colb;
#pragma unroll
  for (int p = 0; p < 4; ++p) {
    f32x4 v = {o[p * 4] * inv, o[p * 4 + 1] * inv, o[p * 4 + 2] * inv,
               o[p * 4 + 3] * inv};
    *(f32x4*)&Og[p * 4] = v;
  }
}

// ---------------------------------------------------------------- launch ----
extern "C" void kernel_launch(void* const* d_in, const int* in_sizes, int n_in,
                              void* d_out, int out_size, void* d_ws,
                              size_t ws_size, hipStream_t stream) {
  const float* x = (const float*)d_in[0];
  const float* wk = (const float*)d_in[1];
  const float* wq = (const float*)d_in[2];
  const float* wv = (const float*)d_in[3];
  float* out = (float*)d_out;
  char* ws = (char*)d_ws;

  u16* Wt = (u16*)ws;
  u16* Qb = (u16*)(ws + 786432);
  u16* Kb = (u16*)(ws + 786432 + 4194304);
  u16* Vt = (u16*)(ws + 786432 + 8388608);
  u16* Opart = (u16*)(ws + 13369344);
  float* ml = (float*)(ws + 49020928);

  const int split = (ws_size >= WS_SPLIT_NEED) ? 1 : 0;

  prep_w_kernel<<<dim3(16, 3), 256, 0, stream>>>(wk, wq, wv, Wt);
  proj_kernel<<<256, 256, 0, stream>>>(x, Wt, Qb, Kb, Vt);
  if (split) {
    attn_kernel<<<4 * EPB, 512, 0, stream>>>(Qb, Kb, Vt, out, Opart, ml, 1);
    combine_kernel<<<dim3(128, 4), 256, 0, stream>>>(Opart, ml, out);
  } else {
    attn_kernel<<<128, 512, 0, stream>>>(Qb, Kb, Vt, out, Opart, ml, 0);
  }
}

// Round 11
// 87.311 us; speedup vs baseline: 1.8218x; 1.0587x over previous
//
#include <hip/hip_runtime.h>
#include <hip/hip_bf16.h>

// Single-head causal self-attention, B=4 T=4096 C=1024 H=128, f32 in/out.
// prep_w: W -> Wt bf16 [3][128][1024] n-major, via LDS transpose (coalesced)
// proj:   fused x@{Wk,Wq,Wv}: 512 blocks x 32 rows (2 blocks/CU resident ->
//         cross-block latency hiding); W staged via global_load_lds
//         (pre-swizzled source, linear LDS); Q prescaled; V transposed.
// attn:   flash causal, 512-thr: QBLK=128 = 8 waves x 16 q-rows, K/V staged
//         via global_load_lds into XOR-swizzled LDS. SWAPPED QK^T: lane holds
//         one q-row's 16 S-values -> softmax is in-lane tree + 2 shfl.
//         kv-split chunk=256, heavy-first, XCD-pinned batch. Partials bf16.
// combine: grid (128,4): 32 rows/block, <=16 partials, 16 acc/thread.
//
// ws map (bytes):
//   Wt    [0,        786432)
//   Qb    [786432,   +4MB)
//   Kb    [+4MB)
//   Vt    [+4MB)                      -> 13369344
//   Opart [13369344, +1088*32KB)      -> 49020928   (bf16)
//   ml    [49020928, +1114112)        -> 50135040

typedef unsigned short u16;
typedef __attribute__((ext_vector_type(8))) __bf16 bf16x8;
typedef __attribute__((ext_vector_type(8))) u16 u16x8;
typedef __attribute__((ext_vector_type(4))) u16 u16x4;
typedef __attribute__((ext_vector_type(4))) float f32x4;

#define T_DIM 4096
#define C_DIM 1024
#define H_DIM 128
#define EPB 272  // entries per batch: sum_{qb<32} ceil((qb+1)/2), chunk=256
#define WS_SPLIT_NEED 50135040ull

static __device__ __forceinline__ f32x4 mfma16x16(u16x8 a, u16x8 b, f32x4 c) {
  return __builtin_amdgcn_mfma_f32_16x16x32_bf16(
      __builtin_bit_cast(bf16x8, a), __builtin_bit_cast(bf16x8, b), c, 0, 0, 0);
}

static __device__ __forceinline__ u16 f2bf(float f) {
  __hip_bfloat16 h = __float2bfloat16(f);
  return __builtin_bit_cast(u16, h);
}

static __device__ __forceinline__ float bf2f(u16 u) {
  unsigned x = (unsigned)u << 16;
  return __builtin_bit_cast(float, x);
}

// async global->LDS, 16B per lane; lptr must be wave-uniform base.
static __device__ __forceinline__ void gll16(const u16* g, u16* l) {
  __builtin_amdgcn_global_load_lds(
      (const __attribute__((address_space(1))) void*)(void*)g,
      (__attribute__((address_space(3))) void*)l, 16, 0, 0);
}

// ---------------------------------------------------------------- prep_w ----
// grid (16, 3): transpose one 64k x 128n slab of W_w via LDS, coalesced both ways.
__global__ __launch_bounds__(256) void prep_w_kernel(
    const float* __restrict__ wk, const float* __restrict__ wq,
    const float* __restrict__ wv, u16* __restrict__ Wt) {
  __shared__ u16 L[64 * 136];
  const int w = blockIdx.y;
  const int k0 = blockIdx.x * 64;
  const float* W = (w == 0) ? wk : (w == 1) ? wq : wv;
  const int t = threadIdx.x;
#pragma unroll
  for (int p = 0; p < 8; ++p) {
    int idx = p * 256 + t;
    int k = idx >> 5, c4 = (idx & 31) * 4;
    float4 v = *(const float4*)&W[(size_t)(k0 + k) * H_DIM + c4];
    u16x4 bv;
    bv.x = f2bf(v.x); bv.y = f2bf(v.y); bv.z = f2bf(v.z); bv.w = f2bf(v.w);
    *(u16x4*)&L[k * 136 + c4] = bv;
  }
  __syncthreads();
#pragma unroll
  for (int p = 0; p < 4; ++p) {
    int cid = p * 256 + t;
    int n = cid >> 3, kc = (cid & 7) * 8;
    u16x8 o;
#pragma unroll
    for (int j = 0; j < 8; ++j) o[j] = L[(kc + j) * 136 + n];
    *(u16x8*)&Wt[(size_t)w * 131072 + (size_t)n * 1024 + k0 + kc] = o;
  }
}

// ------------------------------------------------------------------ proj ----
// 512 blocks x 32 rows, 4 waves all computing (wave owns cols384
// wave*96 + j*16 + lq, j=0..5). 2 blocks/CU resident: the second block's
// MFMAs hide the first's staging drains. W via global_load_lds into
// Wl[384][64] (XOR-swizzled chunks); x staged via regs (f32->bf16).
__global__ __launch_bounds__(256, 2) void proj_kernel(
    const float* __restrict__ x, const u16* __restrict__ Wt,
    u16* __restrict__ Qb, u16* __restrict__ Kb, u16* __restrict__ Vt) {
  __shared__ __attribute__((aligned(16))) u16 smem[32 * 72 + 384 * 64];
  u16* Xl = smem;            // [32][64] pad 72
  u16* Wl = smem + 32 * 72;  // [384][64] linear, XOR-swizzled 16B chunks
  const int m0 = blockIdx.x * 32;
  const int t = threadIdx.x;
  const int wave = t >> 6, lane = t & 63;
  const int g = lane >> 4, lq = lane & 15;
  const int lsw = lq & 7;

  f32x4 acc[2][6] = {};

  for (int k0 = 0; k0 < C_DIM; k0 += 64) {
    __syncthreads();
#pragma unroll
    for (int p = 0; p < 2; ++p) {  // stage x: 32x64 f32 -> bf16 (reg path)
      int idx = p * 256 + t;
      int row = idx >> 4, c4 = (idx & 15) * 4;
      float4 v = *(const float4*)&x[(size_t)(m0 + row) * C_DIM + k0 + c4];
      u16x4 bv;
      bv.x = f2bf(v.x); bv.y = f2bf(v.y); bv.z = f2bf(v.z); bv.w = f2bf(v.w);
      *(u16x4*)&Xl[row * 72 + c4] = bv;
    }
    // stage Wt 384x64 via global_load_lds: issue p covers 8 rows (1KB).
#pragma unroll
    for (int p = 0; p < 12; ++p) {
      int r0 = (wave * 12 + p) * 8;
      int r = r0 + (lane >> 3);
      int csrc = (lane & 7) ^ (lane >> 3);
      gll16(&Wt[(size_t)(r >> 7) * 131072 + (size_t)(r & 127) * 1024 + k0 +
                csrc * 8],
            &Wl[r0 * 64]);
    }
    __syncthreads();
#pragma unroll
    for (int kk = 0; kk < 2; ++kk) {
      u16x8 af[2], bfr[6];
#pragma unroll
      for (int i = 0; i < 2; ++i)
        af[i] = *(const u16x8*)&Xl[(i * 16 + lq) * 72 + kk * 32 + g * 8];
#pragma unroll
      for (int j = 0; j < 6; ++j)
        bfr[j] = *(const u16x8*)&Wl[(wave * 96 + j * 16 + lq) * 64 +
                                    (((kk * 4 + g) ^ lsw) * 8)];
#pragma unroll
      for (int i = 0; i < 2; ++i)
#pragma unroll
        for (int j = 0; j < 6; ++j)
          acc[i][j] = mfma16x16(af[i], bfr[j], acc[i][j]);
    }
  }

  const float qscale = 0.08838834764831845f;  // 128^-0.5
#pragma unroll
  for (int j = 0; j < 6; ++j) {  // K and Q direct writes (wave-uniform branch)
    const int c384 = wave * 96 + j * 16;
    const int which = c384 >> 7;
    const int col = (c384 & 127) + lq;
    if (which == 0) {
#pragma unroll
      for (int i = 0; i < 2; ++i)
#pragma unroll
        for (int r = 0; r < 4; ++r)
          Kb[(size_t)(m0 + i * 16 + g * 4 + r) * H_DIM + col] =
              f2bf(acc[i][j][r]);
    } else if (which == 1) {
#pragma unroll
      for (int i = 0; i < 2; ++i)
#pragma unroll
        for (int r = 0; r < 4; ++r)
          Qb[(size_t)(m0 + i * 16 + g * 4 + r) * H_DIM + col] =
              f2bf(acc[i][j][r] * qscale);
    }
  }
  __syncthreads();
#pragma unroll
  for (int j = 0; j < 6; ++j) {  // V -> LDS transposed [128 h][32 m] pad 40
    const int c384 = wave * 96 + j * 16;
    if ((c384 >> 7) == 2) {
      const int v = (c384 & 127) + lq;
#pragma unroll
      for (int i = 0; i < 2; ++i)
#pragma unroll
        for (int r = 0; r < 4; ++r)
          smem[v * 40 + i * 16 + g * 4 + r] = f2bf(acc[i][j][r]);
    }
  }
  __syncthreads();
  {
    const int b = m0 >> 12;
    const int t0 = m0 & 4095;
#pragma unroll
    for (int p = 0; p < 2; ++p) {
      int idx = p * 256 + t;
      int h = idx >> 2, mc = (idx & 3) * 8;
      *(u16x8*)&Vt[(size_t)b * (H_DIM * T_DIM) + (size_t)h * T_DIM + t0 + mc] =
          *(const u16x8*)&smem[h * 40 + mc];
    }
  }
}

// ------------------------------------------------------------------ attn ----
// 512 threads: 8 waves x 16 q-rows = QBLK 128 sharing one K/V staging via
// global_load_lds (pre-swizzled source). SWAPPED QK^T: s = mfma(K,Q) puts a
// full q-row (16 S values) in each lane -> in-lane softmax tree + 2 shfl.
// split: 1088 blocks, XCD-pinned batch, heavy entries first, chunk=256.
__global__ __launch_bounds__(512, 4) void attn_kernel(
    const u16* __restrict__ Qb, const u16* __restrict__ Kb,
    const u16* __restrict__ Vt, float* __restrict__ out,
    u16* __restrict__ Opart, float* __restrict__ ml, int split) {
  __shared__ __attribute__((aligned(16))) u16 Kl[64 * 128];  // swizzled
  __shared__ __attribute__((aligned(16))) u16 Vl[128 * 64];  // swizzled
  __shared__ __attribute__((aligned(16))) u16 Pl[8][16 * 72];
  const int t = threadIdx.x;
  const int wave = t >> 6, lane = t & 63;
  const int g = lane >> 4, lq = lane & 15;
  const int lsw = lane & 7;  // read-side swizzle key (= row&7 for row=16nf+lq)

  int b, qb, kvb, kve, pid;
  if (split) {
    int bid = (int)blockIdx.x;  // 1088 linear
    int xcd = bid & 7;
    b = xcd >> 1;  // batch pinned to an XCD pair -> K/V L2-local
    int e = (EPB - 1) - ((bid >> 3) * 2 + (bid & 1));  // heavy-first
    int a = 0;
#pragma unroll
    for (int c = 1; c <= 15; ++c)
      if (e >= c * (c + 1)) a = c;
    int off = e - a * (a + 1);
    int d = off / (a + 1);
    int ch = off - d * (a + 1);
    qb = 2 * a + d;
    kvb = ch * 256;
    pid = b * EPB + e;
    int kv_full = qb * 128 + 128;
    kve = (kvb + 256 < kv_full) ? kvb + 256 : kv_full;
  } else {
    b = (int)blockIdx.x & 3;
    qb = 31 - ((int)blockIdx.x >> 2);
    kvb = 0;
    kve = qb * 128 + 128;
    pid = 0;
  }
  const int rowq = qb * 128 + wave * 16;  // wave's first q-row
  const int qrow = rowq + lq;             // this lane's q row (swapped layout)

  u16x8 qf[4];  // 16 q-rows x 128, A-frag layout (prescaled)
  {
    const u16* Qp = Qb + (size_t)(b * T_DIM + qrow) * H_DIM;
#pragma unroll
    for (int c = 0; c < 4; ++c) qf[c] = *(const u16x8*)&Qp[c * 32 + g * 8];
  }

  f32x4 ao[8] = {};
  float m_run = -INFINITY, l_run = 0.f;  // per-lane scalars (q = qrow)

  const u16* Kg0 = Kb + (size_t)b * T_DIM * H_DIM;
  const u16* Vg0 = Vt + (size_t)b * H_DIM * T_DIM;

  for (int kv0 = kvb; kv0 < kve; kv0 += 64) {
    __syncthreads();
    // K tile [64][128]: 2 issues/wave, each 4 rows (1KB).
#pragma unroll
    for (int i = 0; i < 2; ++i) {
      int r0 = (i * 8 + wave) * 4;
      int r = r0 + (lane >> 4);
      int csrc = (lane & 15) ^ (r & 7);
      gll16(&Kg0[(size_t)(kv0 + r) * H_DIM + csrc * 8], &Kl[r0 * 128]);
    }
    // V tile [128][64]: 2 issues/wave, each 8 rows (1KB).
#pragma unroll
    for (int i = 0; i < 2; ++i) {
      int h0 = (i * 8 + wave) * 8;
      int h = h0 + (lane >> 3);
      int csrc = (lane & 7) ^ (lane >> 3);
      gll16(&Vg0[(size_t)h * T_DIM + kv0 + csrc * 8], &Vl[h0 * 64]);
    }
    __syncthreads();

    if (kv0 > rowq + 15) continue;  // fully masked for this wave (uniform)

    // S^T = mfma(K, Q): lane (g,lq) holds S[qrow][kv0 + nf*16 + 4g + r]
    f32x4 s[4];
#pragma unroll
    for (int nf = 0; nf < 4; ++nf) s[nf] = f32x4{0.f, 0.f, 0.f, 0.f};
#pragma unroll
    for (int nf = 0; nf < 4; ++nf)
#pragma unroll
      for (int c = 0; c < 4; ++c) {
        u16x8 kf = *(const u16x8*)&Kl[(nf * 16 + lq) * 128 +
                                      (((c * 4 + g) ^ lsw) * 8)];
        s[nf] = mfma16x16(kf, qf[c], s[nf]);
      }

    if (kv0 + 63 > rowq) {  // diagonal overlap: elementwise causal mask
      const int kb = kv0 + g * 4;
#pragma unroll
      for (int nf = 0; nf < 4; ++nf)
#pragma unroll
        for (int r = 0; r < 4; ++r)
          if (kb + nf * 16 + r > qrow) s[nf][r] = -INFINITY;
    }

    // softmax: in-lane tree over 16 values + cross-g (xor 16, 32)
    float t0 = fmaxf(fmaxf(s[0][0], s[0][1]), fmaxf(s[0][2], s[0][3]));
    float t1 = fmaxf(fmaxf(s[1][0], s[1][1]), fmaxf(s[1][2], s[1][3]));
    float t2 = fmaxf(fmaxf(s[2][0], s[2][1]), fmaxf(s[2][2], s[2][3]));
    float t3 = fmaxf(fmaxf(s[3][0], s[3][1]), fmaxf(s[3][2], s[3][3]));
    float pmax = fmaxf(fmaxf(t0, t1), fmaxf(t2, t3));
    pmax = fmaxf(pmax, __shfl_xor(pmax, 16));
    pmax = fmaxf(pmax, __shfl_xor(pmax, 32));

    float mn = fmaxf(m_run, pmax);
    float al = __expf(m_run - mn);
    m_run = mn;
#pragma unroll
    for (int nf = 0; nf < 4; ++nf)
#pragma unroll
      for (int r = 0; r < 4; ++r) s[nf][r] = __expf(s[nf][r] - mn);
    float u0 = (s[0][0] + s[0][1]) + (s[0][2] + s[0][3]);
    float u1 = (s[1][0] + s[1][1]) + (s[1][2] + s[1][3]);
    float u2 = (s[2][0] + s[2][1]) + (s[2][2] + s[2][3]);
    float u3 = (s[3][0] + s[3][1]) + (s[3][2] + s[3][3]);
    float ps = (u0 + u1) + (u2 + u3);
    ps += __shfl_xor(ps, 16);
    ps += __shfl_xor(ps, 32);
    l_run = l_run * al + ps;

    // defer-rescale: only broadcast+rescale when some row's max moved
    if (!__all(al == 1.f)) {
      float alr[4];
#pragma unroll
      for (int r = 0; r < 4; ++r) alr[r] = __shfl(al, g * 4 + r);
#pragma unroll
      for (int h8 = 0; h8 < 8; ++h8)
#pragma unroll
        for (int r = 0; r < 4; ++r) ao[h8][r] *= alr[r];
    }

    // P (swapped layout) -> per-wave LDS [q=row][k=col] -> A-frags
#pragma unroll
    for (int nf = 0; nf < 4; ++nf)
#pragma unroll
      for (int r = 0; r < 4; ++r)
        Pl[wave][lq * 72 + nf * 16 + g * 4 + r] = f2bf(s[nf][r]);

    u16x8 pf[2];
#pragma unroll
    for (int kk = 0; kk < 2; ++kk)
      pf[kk] = *(const u16x8*)&Pl[wave][lq * 72 + kk * 32 + g * 8];
#pragma unroll
    for (int h8 = 0; h8 < 8; ++h8)
#pragma unroll
      for (int kk = 0; kk < 2; ++kk) {
        u16x8 vf = *(const u16x8*)&Vl[(h8 * 16 + lq) * 64 +
                                      (((kk * 4 + g) ^ lsw) * 8)];
        ao[h8] = mfma16x16(pf[kk], vf, ao[h8]);
      }
  }

  if (!split) {
    float linv = 1.f / l_run;
    float inv[4];
#pragma unroll
    for (int r = 0; r < 4; ++r) inv[r] = __shfl(linv, g * 4 + r);
    float* Og = out + (size_t)(b * T_DIM + rowq) * H_DIM;
#pragma unroll
    for (int h8 = 0; h8 < 8; ++h8)
#pragma unroll
      for (int r = 0; r < 4; ++r)
        Og[(size_t)(g * 4 + r) * H_DIM + h8 * 16 + lq] = ao[h8][r] * inv[r];
  } else {
    u16* Op = Opart + (size_t)pid * 16384 + (size_t)(wave * 16) * H_DIM;
#pragma unroll
    for (int h8 = 0; h8 < 8; ++h8)
#pragma unroll
      for (int r = 0; r < 4; ++r)
        Op[(g * 4 + r) * H_DIM + h8 * 16 + lq] = f2bf(ao[h8][r]);
    if (lane < 16) {  // lane lq holds m/l for q-local row wave*16+lq
      float* mlp = ml + (size_t)pid * 256;
      mlp[wave * 16 + lane] = m_run;
      mlp[128 + wave * 16 + lane] = l_run;
    }
  }
}

// --------------------------------------------------------------- combine ----
// grid (128, 4): 512 blocks; each merges 32 rows of a 128-row q-block
// (<=16 bf16 partials), 16 accumulators/thread.
__global__ __launch_bounds__(256) void combine_kernel(
    const u16* __restrict__ Opart, const float* __restrict__ ml,
    float* __restrict__ out) {
  const int blk = blockIdx.x;
  const int qb = blk >> 2;
  const int sub = blk & 3;
  const int b = blockIdx.y;
  const int t = threadIdx.x;
  const int row = sub * 32 + (t >> 3);  // row within the 128-row q-block
  const int colb = (t & 7) * 16;
  const int a = qb >> 1;
  const int n = a + 1;
  const int base = a * (a + 1) + (qb & 1) * (a + 1);
  const int pid0 = b * EPB + base;

  float M = -INFINITY;
  for (int i = 0; i < n; ++i)
    M = fmaxf(M, ml[(size_t)(pid0 + i) * 256 + row]);

  float L = 0.f;
  float o[16] = {};
  for (int i = 0; i < n; ++i) {
    const size_t mb = (size_t)(pid0 + i) * 256;
    float sc = __expf(ml[mb + row] - M);
    L += sc * ml[mb + 128 + row];
    const u16* Op = Opart + (size_t)(pid0 + i) * 16384 + row * H_DIM + colb;
#pragma unroll
    for (int p = 0; p < 2; ++p) {
      u16x8 v = *(const u16x8*)&Op[p * 8];
#pragma unroll
      for (int e = 0; e < 8; ++e) o[p * 8 + e] += sc * bf2f(v[e]);
    }
  }
  float inv = 1.f / L;
  float* Og = out + ((size_t)b * T_DIM + qb * 128 + row) * H_DIM + colb;
#pragma unroll
  for (int p = 0; p < 4; ++p) {
    f32x4 v = {o[p * 4] * inv, o[p * 4 + 1] * inv, o[p * 4 + 2] * inv,
               o[p * 4 + 3] * inv};
    *(f32x4*)&Og[p * 4] = v;
  }
}

// ---------------------------------------------------------------- launch ----
extern "C" void kernel_launch(void* const* d_in, const int* in_sizes, int n_in,
                              void* d_out, int out_size, void* d_ws,
                              size_t ws_size, hipStream_t stream) {
  const float* x = (const float*)d_in[0];
  const float* wk = (const float*)d_in[1];
  const float* wq = (const float*)d_in[2];
  const float* wv = (const float*)d_in[3];
  float* out = (float*)d_out;
  char* ws = (char*)d_ws;

  u16* Wt = (u16*)ws;
  u16* Qb = (u16*)(ws + 786432);
  u16* Kb = (u16*)(ws + 786432 + 4194304);
  u16* Vt = (u16*)(ws + 786432 + 8388608);
  u16* Opart = (u16*)(ws + 13369344);
  float* ml = (float*)(ws + 49020928);

  const int split = (ws_size >= WS_SPLIT_NEED) ? 1 : 0;

  prep_w_kernel<<<dim3(16, 3), 256, 0, stream>>>(wk, wq, wv, Wt);
  proj_kernel<<<512, 256, 0, stream>>>(x, Wt, Qb, Kb, Vt);
  if (split) {
    attn_kernel<<<4 * EPB, 512, 0, stream>>>(Qb, Kb, Vt, out, Opart, ml, 1);
    combine_kernel<<<dim3(128, 4), 256, 0, stream>>>(Opart, ml, out);
  } else {
    attn_kernel<<<128, 512, 0, stream>>>(Qb, Kb, Vt, out, Opart, ml, 0);
  }
}